// Round 1
// baseline (590.119 us; speedup 1.0000x reference)
//
#include <hip/hip_runtime.h>
#include <hip/hip_bf16.h>
#include <math.h>

#define NNODES 4096
#define MAXD 128

// ---------------------------------------------------------------------------
// CSR build: one block per row, deterministic ordered compaction.
// Each thread owns 16 consecutive columns -> neighbor list is column-sorted.
// ---------------------------------------------------------------------------
__global__ __launch_bounds__(256) void build_csr(const int* __restrict__ adj,
                                                 int* __restrict__ deg,
                                                 int* __restrict__ nbr) {
    int n = blockIdx.x;
    const int* row = adj + (size_t)n * NNODES;
    int t = threadIdx.x;
    __shared__ int cnts[256];
    int c0 = t * 16;
    int cnt = 0;
#pragma unroll
    for (int i = 0; i < 16; i++) cnt += (row[c0 + i] != 0) ? 1 : 0;
    cnts[t] = cnt;
    __syncthreads();
    if (t == 0) {
        int s = 0;
        for (int i = 0; i < 256; i++) { int c = cnts[i]; cnts[i] = s; s += c; }
        deg[n] = (s < MAXD) ? s : MAXD;
    }
    __syncthreads();
    int o = cnts[t];
    int* outr = nbr + (size_t)n * MAXD;
#pragma unroll
    for (int i = 0; i < 16; i++) {
        if (row[c0 + i] != 0) {
            if (o < MAXD) outr[o] = c0 + i;
            o++;
        }
    }
}

// ---------------------------------------------------------------------------
// Per-head GEMM: H[h][m][o] = sum_k X[m][k] * W[h][k][o]
// 64x64 tile, BK=16, 256 threads, 4x4 micro-tile. fp32.
// ---------------------------------------------------------------------------
template<int K, int FOUT>
__global__ __launch_bounds__(256) void gemm_hno(const float* __restrict__ X,
                                                const float* __restrict__ W,
                                                float* __restrict__ Hb) {
    __shared__ float As[16][68];   // As[k][m]
    __shared__ float Bs[16][68];   // Bs[k][n]
    const int h = blockIdx.z;
    const float* Wh = W + (size_t)h * K * FOUT;
    const int m0 = blockIdx.x * 64;
    const int n0 = blockIdx.y * 64;
    const int tid = threadIdx.x;
    const int tm = tid >> 4, tn = tid & 15;
    const int la_m = tid >> 2;          // 0..63
    const int la_k = (tid & 3) * 4;     // 0,4,8,12
    const int lb_k = tid >> 4;          // 0..15
    const int lb_n = (tid & 15) * 4;    // 0..60
    float acc[4][4] = {};
    for (int k0 = 0; k0 < K; k0 += 16) {
        float av[4], bv[4];
#pragma unroll
        for (int i = 0; i < 4; i++) {
            int kk = k0 + la_k + i;
            av[i] = (kk < K) ? X[(size_t)(m0 + la_m) * K + kk] : 0.f;
        }
#pragma unroll
        for (int j = 0; j < 4; j++) {
            int kk = k0 + lb_k;
            int nn = n0 + lb_n + j;
            bv[j] = (kk < K && nn < FOUT) ? Wh[(size_t)kk * FOUT + nn] : 0.f;
        }
        __syncthreads();
#pragma unroll
        for (int i = 0; i < 4; i++) As[la_k + i][la_m] = av[i];
#pragma unroll
        for (int j = 0; j < 4; j++) Bs[lb_k][lb_n + j] = bv[j];
        __syncthreads();
#pragma unroll
        for (int kk = 0; kk < 16; kk++) {
            float a[4], b[4];
#pragma unroll
            for (int i = 0; i < 4; i++) a[i] = As[kk][tm * 4 + i];
#pragma unroll
            for (int j = 0; j < 4; j++) b[j] = Bs[kk][tn * 4 + j];
#pragma unroll
            for (int i = 0; i < 4; i++)
#pragma unroll
                for (int j = 0; j < 4; j++) acc[i][j] += a[i] * b[j];
        }
    }
#pragma unroll
    for (int i = 0; i < 4; i++) {
        int m = m0 + tm * 4 + i;
#pragma unroll
        for (int j = 0; j < 4; j++) {
            int n = n0 + tn * 4 + j;
            if (n < FOUT) Hb[((size_t)h * NNODES + m) * FOUT + n] = acc[i][j];
        }
    }
}

// ---------------------------------------------------------------------------
// es[h][n] = dot(H[h][n][:], a_src[h]); ed likewise. One wave per (h,n).
// ---------------------------------------------------------------------------
template<int FOUT>
__global__ __launch_bounds__(256) void scores_kern(const float* __restrict__ Hb,
                                                   const float* __restrict__ Asrc,
                                                   const float* __restrict__ Adst,
                                                   float* __restrict__ es,
                                                   float* __restrict__ ed) {
    int gw = (blockIdx.x * 256 + threadIdx.x) >> 6;
    int lane = threadIdx.x & 63;
    int h = gw / NNODES;
    int n = gw % NNODES;
    const float* hrow = Hb + ((size_t)h * NNODES + n) * FOUT;
    float s = 0.f, d = 0.f;
    for (int o = lane; o < FOUT; o += 64) {
        float v = hrow[o];
        s += v * Asrc[h * FOUT + o];
        d += v * Adst[h * FOUT + o];
    }
#pragma unroll
    for (int sh = 32; sh >= 1; sh >>= 1) {
        s += __shfl_xor(s, sh);
        d += __shfl_xor(d, sh);
    }
    if (lane == 0) { es[h * NNODES + n] = s; ed[h * NNODES + n] = d; }
}

// ---------------------------------------------------------------------------
// Sparse masked-softmax attention aggregate, layers 1/2 (concat over heads).
// One wave per (h, n). out[n][h*FOUT+o] = ELU(sum_m alpha*h[m][o]) (+res)
// ---------------------------------------------------------------------------
template<int FOUT, int HEADS, bool RES>
__global__ __launch_bounds__(256) void aggregate_kern(const float* __restrict__ Hb,
                                                      const float* __restrict__ es,
                                                      const float* __restrict__ ed,
                                                      const int* __restrict__ deg,
                                                      const int* __restrict__ nbr,
                                                      const float* __restrict__ residual,
                                                      float* __restrict__ outp) {
    int gw = (blockIdx.x * 256 + threadIdx.x) >> 6;
    int lane = threadIdx.x & 63;
    int h = gw / NNODES;
    int n = gw % NNODES;
    int d = deg[n];
    const int* nb = nbr + (size_t)n * MAXD;
    float esn = es[h * NNODES + n];
    float sc[2];
    int nm[2];
    float mx = -INFINITY;
#pragma unroll
    for (int r = 0; r < 2; r++) {
        int j = lane + r * 64;
        int m = (j < d) ? nb[j] : 0;
        nm[r] = m;
        float e = -INFINITY;
        if (j < d) {
            float t = esn + ed[h * NNODES + m];
            e = (t > 0.f) ? t : 0.2f * t;
        }
        sc[r] = e;
        mx = fmaxf(mx, e);
    }
#pragma unroll
    for (int sh = 32; sh >= 1; sh >>= 1) mx = fmaxf(mx, __shfl_xor(mx, sh));
    float sum = 0.f;
#pragma unroll
    for (int r = 0; r < 2; r++) {
        float ex = (sc[r] == -INFINITY) ? 0.f : expf(sc[r] - mx);
        sc[r] = ex;
        sum += ex;
    }
#pragma unroll
    for (int sh = 32; sh >= 1; sh >>= 1) sum += __shfl_xor(sum, sh);
    float inv = 1.f / sum;
    sc[0] *= inv; sc[1] *= inv;
    constexpr int Q = FOUT / 64;
    float acc[Q] = {};
    for (int j = 0; j < d; j++) {
        float a = __shfl(sc[j >> 6], j & 63);
        int m = __shfl(nm[j >> 6], j & 63);
        const float* hrow = Hb + ((size_t)h * NNODES + m) * FOUT;
#pragma unroll
        for (int q = 0; q < Q; q++) acc[q] += a * hrow[lane + q * 64];
    }
#pragma unroll
    for (int q = 0; q < Q; q++) {
        float v = acc[q];
        v = (v > 0.f) ? v : (expf(v) - 1.f);   // ELU
        size_t idx = (size_t)n * (HEADS * FOUT) + (size_t)h * FOUT + lane + q * 64;
        if (RES) v += residual[idx];
        outp[idx] = v;
    }
}

// ---------------------------------------------------------------------------
// Layer 3: aggregate, mean over 6 heads, then row log_softmax (121 classes).
// One wave per node n. lane covers o=lane and o=lane+64 (<121).
// ---------------------------------------------------------------------------
__global__ __launch_bounds__(256) void aggregate3_kern(const float* __restrict__ Hb,
                                                       const float* __restrict__ es,
                                                       const float* __restrict__ ed,
                                                       const int* __restrict__ deg,
                                                       const int* __restrict__ nbr,
                                                       float* __restrict__ outp) {
    constexpr int FOUT = 121, HEADS = 6;
    int gw = (blockIdx.x * 256 + threadIdx.x) >> 6;
    int lane = threadIdx.x & 63;
    int n = gw;
    if (n >= NNODES) return;
    int d = deg[n];
    const int* nb = nbr + (size_t)n * MAXD;
    float acc0 = 0.f, acc1 = 0.f;
    for (int h = 0; h < HEADS; h++) {
        float esn = es[h * NNODES + n];
        float sc[2];
        int nm[2];
        float mx = -INFINITY;
#pragma unroll
        for (int r = 0; r < 2; r++) {
            int j = lane + r * 64;
            int m = (j < d) ? nb[j] : 0;
            nm[r] = m;
            float e = -INFINITY;
            if (j < d) {
                float t = esn + ed[h * NNODES + m];
                e = (t > 0.f) ? t : 0.2f * t;
            }
            sc[r] = e;
            mx = fmaxf(mx, e);
        }
#pragma unroll
        for (int sh = 32; sh >= 1; sh >>= 1) mx = fmaxf(mx, __shfl_xor(mx, sh));
        float sum = 0.f;
#pragma unroll
        for (int r = 0; r < 2; r++) {
            float ex = (sc[r] == -INFINITY) ? 0.f : expf(sc[r] - mx);
            sc[r] = ex;
            sum += ex;
        }
#pragma unroll
        for (int sh = 32; sh >= 1; sh >>= 1) sum += __shfl_xor(sum, sh);
        float inv = 1.f / sum;
        sc[0] *= inv; sc[1] *= inv;
        for (int j = 0; j < d; j++) {
            float a = __shfl(sc[j >> 6], j & 63);
            int m = __shfl(nm[j >> 6], j & 63);
            const float* hrow = Hb + ((size_t)h * NNODES + m) * FOUT;
            acc0 += a * hrow[lane];
            if (lane < FOUT - 64) acc1 += a * hrow[lane + 64];
        }
    }
    float l0 = acc0 * (1.f / 6.f);
    float l1 = acc1 * (1.f / 6.f);
    // row log_softmax
    float mx = l0;
    if (lane < FOUT - 64) mx = fmaxf(mx, l1);
#pragma unroll
    for (int sh = 32; sh >= 1; sh >>= 1) mx = fmaxf(mx, __shfl_xor(mx, sh));
    float s = expf(l0 - mx) + ((lane < FOUT - 64) ? expf(l1 - mx) : 0.f);
#pragma unroll
    for (int sh = 32; sh >= 1; sh >>= 1) s += __shfl_xor(s, sh);
    float lse = logf(s);
    outp[(size_t)n * FOUT + lane] = l0 - mx - lse;
    if (lane < FOUT - 64) outp[(size_t)n * FOUT + 64 + lane] = l1 - mx - lse;
}

// ---------------------------------------------------------------------------
extern "C" void kernel_launch(void* const* d_in, const int* in_sizes, int n_in,
                              void* d_out, int out_size, void* d_ws, size_t ws_size,
                              hipStream_t stream) {
    const float* x   = (const float*)d_in[0];
    const int*   adj = (const int*)d_in[1];
    const float* W1  = (const float*)d_in[2];
    const float* a1s = (const float*)d_in[3];
    const float* a1d = (const float*)d_in[4];
    const float* W2  = (const float*)d_in[5];
    const float* a2s = (const float*)d_in[6];
    const float* a2d = (const float*)d_in[7];
    const float* W3  = (const float*)d_in[8];
    const float* a3s = (const float*)d_in[9];
    const float* a3d = (const float*)d_in[10];
    float* outp = (float*)d_out;

    char* w = (char*)d_ws;
    int* deg = (int*)w;   w += (size_t)NNODES * sizeof(int);
    int* nbr = (int*)w;   w += (size_t)NNODES * MAXD * sizeof(int);
    float* hbuf = (float*)w; w += (size_t)4 * NNODES * 256 * sizeof(float);  // 16 MB, also fits 6*N*121
    float* es = (float*)w;   w += (size_t)6 * NNODES * sizeof(float);
    float* ed = (float*)w;   w += (size_t)6 * NNODES * sizeof(float);
    float* x1 = (float*)w;   w += (size_t)NNODES * 1024 * sizeof(float);
    float* x2 = (float*)w;   w += (size_t)NNODES * 1024 * sizeof(float);

    build_csr<<<NNODES, 256, 0, stream>>>(adj, deg, nbr);

    // ---- Layer 1: x[4096,50] -> x1[4096,1024]
    gemm_hno<50, 256><<<dim3(64, 4, 4), 256, 0, stream>>>(x, W1, hbuf);
    scores_kern<256><<<4 * NNODES / 4, 256, 0, stream>>>(hbuf, a1s, a1d, es, ed);
    aggregate_kern<256, 4, false><<<4 * NNODES / 4, 256, 0, stream>>>(
        hbuf, es, ed, deg, nbr, nullptr, x1);

    // ---- Layer 2: x1 -> x2 = ELU(gat(x1)) + x1
    gemm_hno<1024, 256><<<dim3(64, 4, 4), 256, 0, stream>>>(x1, W2, hbuf);
    scores_kern<256><<<4 * NNODES / 4, 256, 0, stream>>>(hbuf, a2s, a2d, es, ed);
    aggregate_kern<256, 4, true><<<4 * NNODES / 4, 256, 0, stream>>>(
        hbuf, es, ed, deg, nbr, x1, x2);

    // ---- Layer 3: x2 -> out = log_softmax(mean_h gat(x2))
    gemm_hno<1024, 121><<<dim3(64, 2, 6), 256, 0, stream>>>(x2, W3, hbuf);
    scores_kern<121><<<6 * NNODES / 4, 256, 0, stream>>>(hbuf, a3s, a3d, es, ed);
    aggregate3_kern<<<NNODES / 4, 256, 0, stream>>>(hbuf, es, ed, deg, nbr, outp);
}

// Round 2
// 302.413 us; speedup vs baseline: 1.9514x; 1.9514x over previous
//
#include <hip/hip_runtime.h>
#include <hip/hip_bf16.h>
#include <math.h>

#define NNODES 4096
#define MAXD 128

typedef __attribute__((ext_vector_type(8))) short bf16x8;
typedef __attribute__((ext_vector_type(4))) float f32x4;

__device__ inline ushort f32_to_bf16_rne(float f) {
    uint32_t u = __float_as_uint(f);
    u += 0x7FFFu + ((u >> 16) & 1u);
    return (ushort)(u >> 16);
}
__device__ inline float bf16_to_f32(ushort h) {
    return __uint_as_float((uint32_t)h << 16);
}

// ---------------------------------------------------------------------------
// CSR build: one block per row, deterministic ordered compaction.
// ---------------------------------------------------------------------------
__global__ __launch_bounds__(256) void build_csr(const int* __restrict__ adj,
                                                 int* __restrict__ deg,
                                                 int* __restrict__ nbr) {
    int n = blockIdx.x;
    const int* row = adj + (size_t)n * NNODES;
    int t = threadIdx.x;
    __shared__ int cnts[256];
    int c0 = t * 16;
    int cnt = 0;
#pragma unroll
    for (int i = 0; i < 16; i++) cnt += (row[c0 + i] != 0) ? 1 : 0;
    cnts[t] = cnt;
    __syncthreads();
    if (t == 0) {
        int s = 0;
        for (int i = 0; i < 256; i++) { int c = cnts[i]; cnts[i] = s; s += c; }
        deg[n] = (s < MAXD) ? s : MAXD;
    }
    __syncthreads();
    int o = cnts[t];
    int* outr = nbr + (size_t)n * MAXD;
#pragma unroll
    for (int i = 0; i < 16; i++) {
        if (row[c0 + i] != 0) {
            if (o < MAXD) outr[o] = c0 + i;
            o++;
        }
    }
}

// ---------------------------------------------------------------------------
// Split X [M][K] fp32 -> hi/lo bf16 [M][KP] (zero-pad k>=K). KP power of 2.
// ---------------------------------------------------------------------------
__global__ __launch_bounds__(256) void xsplit(const float* __restrict__ X,
                                              ushort* __restrict__ Xhi,
                                              ushort* __restrict__ Xlo,
                                              int M, int K, int KP_log2) {
    int KP = 1 << KP_log2;
    int total = M << KP_log2;
    for (int i = blockIdx.x * 256 + threadIdx.x; i < total; i += gridDim.x * 256) {
        int k = i & (KP - 1);
        int m = i >> KP_log2;
        float v = (k < K) ? X[(size_t)m * K + k] : 0.f;
        ushort hi = f32_to_bf16_rne(v);
        float hf = bf16_to_f32(hi);
        Xhi[i] = hi;
        Xlo[i] = f32_to_bf16_rne(v - hf);
    }
}

// ---------------------------------------------------------------------------
// Transpose-split W [H][K][N] fp32 -> Wt hi/lo [H][NP][KP] bf16, zero-padded.
// ---------------------------------------------------------------------------
__global__ __launch_bounds__(256) void wsplit(const float* __restrict__ W,
                                              ushort* __restrict__ Whi,
                                              ushort* __restrict__ Wlo,
                                              int K, int KP, int N, int NP) {
    __shared__ float tile[32][33];
    int h = blockIdx.z;
    int k0 = blockIdx.x * 32, n0 = blockIdx.y * 32;
    int tid = threadIdx.x;
    const float* Wh_ = W + (size_t)h * K * N;
#pragma unroll
    for (int r = 0; r < 4; r++) {
        int kl = (tid >> 5) + r * 8;
        int nl = tid & 31;
        int k = k0 + kl, n = n0 + nl;
        tile[kl][nl] = (k < K && n < N) ? Wh_[(size_t)k * N + n] : 0.f;
    }
    __syncthreads();
#pragma unroll
    for (int r = 0; r < 4; r++) {
        int nl = (tid >> 5) + r * 8;
        int kl = tid & 31;
        float v = tile[kl][nl];
        ushort hi = f32_to_bf16_rne(v);
        float hf = bf16_to_f32(hi);
        ushort lo = f32_to_bf16_rne(v - hf);
        size_t o = ((size_t)h * NP + n0 + nl) * KP + k0 + kl;
        Whi[o] = hi;
        Wlo[o] = lo;
    }
}

// ---------------------------------------------------------------------------
// Split-precision bf16 MFMA GEMM: Hb[h][m][n] = sum_k X[m][k]*W[h][k][n]
// X as hi/lo [M][KP]; W as transposed hi/lo [H][NP][KP].
// Block 128x128 (4 waves, 64x64 wave tiles), K-step 32, 16x16x32 MFMA.
// h = Xhi*Whi + Xhi*Wlo + Xlo*Whi  (fp32 accumulate) ~ fp32 accuracy.
// ---------------------------------------------------------------------------
__global__ __launch_bounds__(256) void gemm_mfma(const ushort* __restrict__ Xhi,
                                                 const ushort* __restrict__ Xlo,
                                                 const ushort* __restrict__ Whi,
                                                 const ushort* __restrict__ Wlo,
                                                 float* __restrict__ Hb,
                                                 int KP, int NP, int Nreal) {
    __shared__ ushort Ah[128][40], Al[128][40], Bh[128][40], Bl[128][40];
    const int h = blockIdx.z;
    const int m0 = blockIdx.x * 128;
    const int n0 = blockIdx.y * 128;
    const int tid = threadIdx.x;
    const int lane = tid & 63;
    const int w = tid >> 6;
    const int wr = (w >> 1) * 64, wc = (w & 1) * 64;
    const int fr = lane & 15, fg = lane >> 4;
    const ushort* Wh_ = Whi + (size_t)h * NP * KP;
    const ushort* Wl_ = Wlo + (size_t)h * NP * KP;
    f32x4 acc[4][4] = {};
    for (int k0 = 0; k0 < KP; k0 += 32) {
        __syncthreads();
#pragma unroll
        for (int r = 0; r < 2; r++) {
            int c = tid + 256 * r;
            int row = c >> 2, kc = (c & 3) * 8;
            *(bf16x8*)&Ah[row][kc] = *(const bf16x8*)&Xhi[(size_t)(m0 + row) * KP + k0 + kc];
            *(bf16x8*)&Al[row][kc] = *(const bf16x8*)&Xlo[(size_t)(m0 + row) * KP + k0 + kc];
            *(bf16x8*)&Bh[row][kc] = *(const bf16x8*)&Wh_[(size_t)(n0 + row) * KP + k0 + kc];
            *(bf16x8*)&Bl[row][kc] = *(const bf16x8*)&Wl_[(size_t)(n0 + row) * KP + k0 + kc];
        }
        __syncthreads();
        bf16x8 ah[4], al[4], bh[4], bl[4];
#pragma unroll
        for (int i = 0; i < 4; i++) {
            ah[i] = *(const bf16x8*)&Ah[wr + i * 16 + fr][fg * 8];
            al[i] = *(const bf16x8*)&Al[wr + i * 16 + fr][fg * 8];
            bh[i] = *(const bf16x8*)&Bh[wc + i * 16 + fr][fg * 8];
            bl[i] = *(const bf16x8*)&Bl[wc + i * 16 + fr][fg * 8];
        }
#pragma unroll
        for (int i = 0; i < 4; i++)
#pragma unroll
            for (int j = 0; j < 4; j++) {
                acc[i][j] = __builtin_amdgcn_mfma_f32_16x16x32_bf16(ah[i], bh[j], acc[i][j], 0, 0, 0);
                acc[i][j] = __builtin_amdgcn_mfma_f32_16x16x32_bf16(ah[i], bl[j], acc[i][j], 0, 0, 0);
                acc[i][j] = __builtin_amdgcn_mfma_f32_16x16x32_bf16(al[i], bh[j], acc[i][j], 0, 0, 0);
            }
    }
    // epilogue: D row = (fg*4 + r), col = fr within each 16x16 fragment
#pragma unroll
    for (int i = 0; i < 4; i++)
#pragma unroll
        for (int j = 0; j < 4; j++)
#pragma unroll
            for (int r = 0; r < 4; r++) {
                int row = m0 + wr + i * 16 + fg * 4 + r;
                int col = n0 + wc + j * 16 + fr;
                if (col < Nreal)
                    Hb[((size_t)h * NNODES + row) * Nreal + col] = acc[i][j][r];
            }
}

// ---------------------------------------------------------------------------
// es[h][n] = dot(H[h][n][:], a_src[h]); ed likewise. One wave per (h,n).
// ---------------------------------------------------------------------------
template<int FOUT>
__global__ __launch_bounds__(256) void scores_kern(const float* __restrict__ Hb,
                                                   const float* __restrict__ Asrc,
                                                   const float* __restrict__ Adst,
                                                   float* __restrict__ es,
                                                   float* __restrict__ ed) {
    int gw = (blockIdx.x * 256 + threadIdx.x) >> 6;
    int lane = threadIdx.x & 63;
    int h = gw / NNODES;
    int n = gw % NNODES;
    const float* hrow = Hb + ((size_t)h * NNODES + n) * FOUT;
    float s = 0.f, d = 0.f;
    for (int o = lane; o < FOUT; o += 64) {
        float v = hrow[o];
        s += v * Asrc[h * FOUT + o];
        d += v * Adst[h * FOUT + o];
    }
#pragma unroll
    for (int sh = 32; sh >= 1; sh >>= 1) {
        s += __shfl_xor(s, sh);
        d += __shfl_xor(d, sh);
    }
    if (lane == 0) { es[h * NNODES + n] = s; ed[h * NNODES + n] = d; }
}

// ---------------------------------------------------------------------------
// Sparse masked-softmax attention aggregate, layers 1/2 (concat over heads).
// ---------------------------------------------------------------------------
template<int FOUT, int HEADS, bool RES>
__global__ __launch_bounds__(256) void aggregate_kern(const float* __restrict__ Hb,
                                                      const float* __restrict__ es,
                                                      const float* __restrict__ ed,
                                                      const int* __restrict__ deg,
                                                      const int* __restrict__ nbr,
                                                      const float* __restrict__ residual,
                                                      float* __restrict__ outp) {
    int gw = (blockIdx.x * 256 + threadIdx.x) >> 6;
    int lane = threadIdx.x & 63;
    int h = gw / NNODES;
    int n = gw % NNODES;
    int d = deg[n];
    const int* nb = nbr + (size_t)n * MAXD;
    float esn = es[h * NNODES + n];
    float sc[2];
    int nm[2];
    float mx = -INFINITY;
#pragma unroll
    for (int r = 0; r < 2; r++) {
        int j = lane + r * 64;
        int m = (j < d) ? nb[j] : 0;
        nm[r] = m;
        float e = -INFINITY;
        if (j < d) {
            float t = esn + ed[h * NNODES + m];
            e = (t > 0.f) ? t : 0.2f * t;
        }
        sc[r] = e;
        mx = fmaxf(mx, e);
    }
#pragma unroll
    for (int sh = 32; sh >= 1; sh >>= 1) mx = fmaxf(mx, __shfl_xor(mx, sh));
    float sum = 0.f;
#pragma unroll
    for (int r = 0; r < 2; r++) {
        float ex = (sc[r] == -INFINITY) ? 0.f : expf(sc[r] - mx);
        sc[r] = ex;
        sum += ex;
    }
#pragma unroll
    for (int sh = 32; sh >= 1; sh >>= 1) sum += __shfl_xor(sum, sh);
    float inv = 1.f / sum;
    sc[0] *= inv; sc[1] *= inv;
    constexpr int Q = FOUT / 64;
    float acc[Q] = {};
    for (int j = 0; j < d; j++) {
        float a = __shfl(sc[j >> 6], j & 63);
        int m = __shfl(nm[j >> 6], j & 63);
        const float* hrow = Hb + ((size_t)h * NNODES + m) * FOUT;
#pragma unroll
        for (int q = 0; q < Q; q++) acc[q] += a * hrow[lane + q * 64];
    }
#pragma unroll
    for (int q = 0; q < Q; q++) {
        float v = acc[q];
        v = (v > 0.f) ? v : (expf(v) - 1.f);   // ELU
        size_t idx = (size_t)n * (HEADS * FOUT) + (size_t)h * FOUT + lane + q * 64;
        if (RES) v += residual[idx];
        outp[idx] = v;
    }
}

// ---------------------------------------------------------------------------
// Layer 3: aggregate, mean over 6 heads, then row log_softmax (121 classes).
// ---------------------------------------------------------------------------
__global__ __launch_bounds__(256) void aggregate3_kern(const float* __restrict__ Hb,
                                                       const float* __restrict__ es,
                                                       const float* __restrict__ ed,
                                                       const int* __restrict__ deg,
                                                       const int* __restrict__ nbr,
                                                       float* __restrict__ outp) {
    constexpr int FOUT = 121, HEADS = 6;
    int gw = (blockIdx.x * 256 + threadIdx.x) >> 6;
    int lane = threadIdx.x & 63;
    int n = gw;
    if (n >= NNODES) return;
    int d = deg[n];
    const int* nb = nbr + (size_t)n * MAXD;
    float acc0 = 0.f, acc1 = 0.f;
    for (int h = 0; h < HEADS; h++) {
        float esn = es[h * NNODES + n];
        float sc[2];
        int nm[2];
        float mx = -INFINITY;
#pragma unroll
        for (int r = 0; r < 2; r++) {
            int j = lane + r * 64;
            int m = (j < d) ? nb[j] : 0;
            nm[r] = m;
            float e = -INFINITY;
            if (j < d) {
                float t = esn + ed[h * NNODES + m];
                e = (t > 0.f) ? t : 0.2f * t;
            }
            sc[r] = e;
            mx = fmaxf(mx, e);
        }
#pragma unroll
        for (int sh = 32; sh >= 1; sh >>= 1) mx = fmaxf(mx, __shfl_xor(mx, sh));
        float sum = 0.f;
#pragma unroll
        for (int r = 0; r < 2; r++) {
            float ex = (sc[r] == -INFINITY) ? 0.f : expf(sc[r] - mx);
            sc[r] = ex;
            sum += ex;
        }
#pragma unroll
        for (int sh = 32; sh >= 1; sh >>= 1) sum += __shfl_xor(sum, sh);
        float inv = 1.f / sum;
        sc[0] *= inv; sc[1] *= inv;
        for (int j = 0; j < d; j++) {
            float a = __shfl(sc[j >> 6], j & 63);
            int m = __shfl(nm[j >> 6], j & 63);
            const float* hrow = Hb + ((size_t)h * NNODES + m) * FOUT;
            acc0 += a * hrow[lane];
            if (lane < FOUT - 64) acc1 += a * hrow[lane + 64];
        }
    }
    float l0 = acc0 * (1.f / 6.f);
    float l1 = acc1 * (1.f / 6.f);
    float mx = l0;
    if (lane < FOUT - 64) mx = fmaxf(mx, l1);
#pragma unroll
    for (int sh = 32; sh >= 1; sh >>= 1) mx = fmaxf(mx, __shfl_xor(mx, sh));
    float s = expf(l0 - mx) + ((lane < FOUT - 64) ? expf(l1 - mx) : 0.f);
#pragma unroll
    for (int sh = 32; sh >= 1; sh >>= 1) s += __shfl_xor(s, sh);
    float lse = logf(s);
    outp[(size_t)n * FOUT + lane] = l0 - mx - lse;
    if (lane < FOUT - 64) outp[(size_t)n * FOUT + 64 + lane] = l1 - mx - lse;
}

// ---------------------------------------------------------------------------
extern "C" void kernel_launch(void* const* d_in, const int* in_sizes, int n_in,
                              void* d_out, int out_size, void* d_ws, size_t ws_size,
                              hipStream_t stream) {
    const float* x   = (const float*)d_in[0];
    const int*   adj = (const int*)d_in[1];
    const float* W1  = (const float*)d_in[2];
    const float* a1s = (const float*)d_in[3];
    const float* a1d = (const float*)d_in[4];
    const float* W2  = (const float*)d_in[5];
    const float* a2s = (const float*)d_in[6];
    const float* a2d = (const float*)d_in[7];
    const float* W3  = (const float*)d_in[8];
    const float* a3s = (const float*)d_in[9];
    const float* a3d = (const float*)d_in[10];
    float* outp = (float*)d_out;

    char* w = (char*)d_ws;
    int* deg = (int*)w;      w += (size_t)NNODES * sizeof(int);
    int* nbr = (int*)w;      w += (size_t)NNODES * MAXD * sizeof(int);
    float* hbuf = (float*)w; w += (size_t)4 * NNODES * 256 * sizeof(float);  // 16 MB (also fits 6*N*121)
    float* es = (float*)w;   w += (size_t)6 * NNODES * sizeof(float);
    float* ed = (float*)w;   w += (size_t)6 * NNODES * sizeof(float);
    float* x1 = (float*)w;   w += (size_t)NNODES * 1024 * sizeof(float);
    float* x2 = (float*)w;   w += (size_t)NNODES * 1024 * sizeof(float);
    ushort* Xhi = (ushort*)w; w += (size_t)NNODES * 1024 * sizeof(ushort);   // shared for x/x1/x2
    ushort* Xlo = (ushort*)w; w += (size_t)NNODES * 1024 * sizeof(ushort);
    ushort* W1h = (ushort*)w; w += (size_t)4 * 256 * 64 * sizeof(ushort);
    ushort* W1l = (ushort*)w; w += (size_t)4 * 256 * 64 * sizeof(ushort);
    ushort* W2h = (ushort*)w; w += (size_t)4 * 256 * 1024 * sizeof(ushort);
    ushort* W2l = (ushort*)w; w += (size_t)4 * 256 * 1024 * sizeof(ushort);
    ushort* W3h = (ushort*)w; w += (size_t)6 * 128 * 1024 * sizeof(ushort);
    ushort* W3l = (ushort*)w; w += (size_t)6 * 128 * 1024 * sizeof(ushort);

    build_csr<<<NNODES, 256, 0, stream>>>(adj, deg, nbr);

    // Weight transpose+split (independent of layer outputs)
    wsplit<<<dim3(2, 8, 4), 256, 0, stream>>>(W1, W1h, W1l, 50, 64, 256, 256);
    wsplit<<<dim3(32, 8, 4), 256, 0, stream>>>(W2, W2h, W2l, 1024, 1024, 256, 256);
    wsplit<<<dim3(32, 4, 6), 256, 0, stream>>>(W3, W3h, W3l, 1024, 1024, 121, 128);

    // ---- Layer 1: x[4096,50] -> x1[4096,1024]
    xsplit<<<1024, 256, 0, stream>>>(x, Xhi, Xlo, NNODES, 50, 6);
    gemm_mfma<<<dim3(32, 2, 4), 256, 0, stream>>>(Xhi, Xlo, W1h, W1l, hbuf, 64, 256, 256);
    scores_kern<256><<<4 * NNODES / 4, 256, 0, stream>>>(hbuf, a1s, a1d, es, ed);
    aggregate_kern<256, 4, false><<<4 * NNODES / 4, 256, 0, stream>>>(
        hbuf, es, ed, deg, nbr, nullptr, x1);

    // ---- Layer 2: x1 -> x2 = ELU(gat(x1)) + x1
    xsplit<<<2048, 256, 0, stream>>>(x1, Xhi, Xlo, NNODES, 1024, 10);
    gemm_mfma<<<dim3(32, 2, 4), 256, 0, stream>>>(Xhi, Xlo, W2h, W2l, hbuf, 1024, 256, 256);
    scores_kern<256><<<4 * NNODES / 4, 256, 0, stream>>>(hbuf, a2s, a2d, es, ed);
    aggregate_kern<256, 4, true><<<4 * NNODES / 4, 256, 0, stream>>>(
        hbuf, es, ed, deg, nbr, x1, x2);

    // ---- Layer 3: x2 -> out = log_softmax(mean_h gat(x2))
    xsplit<<<2048, 256, 0, stream>>>(x2, Xhi, Xlo, NNODES, 1024, 10);
    gemm_mfma<<<dim3(32, 1, 6), 256, 0, stream>>>(Xhi, Xlo, W3h, W3l, hbuf, 1024, 128, 121);
    scores_kern<121><<<6 * NNODES / 4, 256, 0, stream>>>(hbuf, a3s, a3d, es, ed);
    aggregate3_kern<<<NNODES / 4, 256, 0, stream>>>(hbuf, es, ed, deg, nbr, outp);
}

// Round 3
// 246.141 us; speedup vs baseline: 2.3975x; 1.2286x over previous
//
#include <hip/hip_runtime.h>
#include <hip/hip_bf16.h>
#include <math.h>

#define NNODES 4096
#define MAXD 128

typedef __attribute__((ext_vector_type(8))) short bf16x8;
typedef __attribute__((ext_vector_type(4))) float f32x4;

__device__ inline ushort f32_to_bf16_rne(float f) {
    uint32_t u = __float_as_uint(f);
    u += 0x7FFFu + ((u >> 16) & 1u);
    return (ushort)(u >> 16);
}
__device__ inline float bf16_to_f32(ushort h) {
    return __uint_as_float((uint32_t)h << 16);
}

// ---------------------------------------------------------------------------
// CSR build: one block per row, deterministic ordered compaction.
// ---------------------------------------------------------------------------
__global__ __launch_bounds__(256) void build_csr(const int* __restrict__ adj,
                                                 int* __restrict__ deg,
                                                 int* __restrict__ nbr) {
    int n = blockIdx.x;
    const int* row = adj + (size_t)n * NNODES;
    int t = threadIdx.x;
    __shared__ int cnts[256];
    int c0 = t * 16;
    int cnt = 0;
#pragma unroll
    for (int i = 0; i < 16; i++) cnt += (row[c0 + i] != 0) ? 1 : 0;
    cnts[t] = cnt;
    __syncthreads();
    if (t == 0) {
        int s = 0;
        for (int i = 0; i < 256; i++) { int c = cnts[i]; cnts[i] = s; s += c; }
        deg[n] = (s < MAXD) ? s : MAXD;
    }
    __syncthreads();
    int o = cnts[t];
    int* outr = nbr + (size_t)n * MAXD;
#pragma unroll
    for (int i = 0; i < 16; i++) {
        if (row[c0 + i] != 0) {
            if (o < MAXD) outr[o] = c0 + i;
            o++;
        }
    }
}

// ---------------------------------------------------------------------------
// Split X [M][K] fp32 -> hi/lo bf16 [M][KP] (zero-pad k>=K). KP power of 2.
// ---------------------------------------------------------------------------
__global__ __launch_bounds__(256) void xsplit(const float* __restrict__ X,
                                              ushort* __restrict__ Xhi,
                                              ushort* __restrict__ Xlo,
                                              int M, int K, int KP_log2) {
    int KP = 1 << KP_log2;
    int total = M << KP_log2;
    for (int i = blockIdx.x * 256 + threadIdx.x; i < total; i += gridDim.x * 256) {
        int k = i & (KP - 1);
        int m = i >> KP_log2;
        float v = (k < K) ? X[(size_t)m * K + k] : 0.f;
        ushort hi = f32_to_bf16_rne(v);
        float hf = bf16_to_f32(hi);
        Xhi[i] = hi;
        Xlo[i] = f32_to_bf16_rne(v - hf);
    }
}

// ---------------------------------------------------------------------------
// Transpose-split W [H][K][N] fp32 -> Wt hi/lo [H][NP][KP] bf16, zero-padded.
// ---------------------------------------------------------------------------
__global__ __launch_bounds__(256) void wsplit(const float* __restrict__ W,
                                              ushort* __restrict__ Whi,
                                              ushort* __restrict__ Wlo,
                                              int K, int KP, int N, int NP) {
    __shared__ float tile[32][33];
    int h = blockIdx.z;
    int k0 = blockIdx.x * 32, n0 = blockIdx.y * 32;
    int tid = threadIdx.x;
    const float* Wh_ = W + (size_t)h * K * N;
#pragma unroll
    for (int r = 0; r < 4; r++) {
        int kl = (tid >> 5) + r * 8;
        int nl = tid & 31;
        int k = k0 + kl, n = n0 + nl;
        tile[kl][nl] = (k < K && n < N) ? Wh_[(size_t)k * N + n] : 0.f;
    }
    __syncthreads();
#pragma unroll
    for (int r = 0; r < 4; r++) {
        int nl = (tid >> 5) + r * 8;
        int kl = tid & 31;
        float v = tile[kl][nl];
        ushort hi = f32_to_bf16_rne(v);
        float hf = bf16_to_f32(hi);
        ushort lo = f32_to_bf16_rne(v - hf);
        size_t o = ((size_t)h * NP + n0 + nl) * KP + k0 + kl;
        Whi[o] = hi;
        Wlo[o] = lo;
    }
}

// ---------------------------------------------------------------------------
// Split-precision bf16 MFMA GEMM: Hb[h][m][n] = sum_k X[m][k]*W[h][k][n]
// Block tile 128x64 (4 waves, 64x32 wave tiles), K-step 32, 16x16x32 MFMA.
// h = Xhi*Whi + Xhi*Wlo + Xlo*Whi  (fp32 accumulate) ~ fp32 accuracy.
// ---------------------------------------------------------------------------
__global__ __launch_bounds__(256) void gemm_mfma(const ushort* __restrict__ Xhi,
                                                 const ushort* __restrict__ Xlo,
                                                 const ushort* __restrict__ Whi,
                                                 const ushort* __restrict__ Wlo,
                                                 float* __restrict__ Hb,
                                                 int KP, int NP, int Nreal) {
    __shared__ ushort Ah[128][40], Al[128][40], Bh[64][40], Bl[64][40];
    const int h = blockIdx.z;
    const int m0 = blockIdx.x * 128;
    const int n0 = blockIdx.y * 64;
    const int tid = threadIdx.x;
    const int lane = tid & 63;
    const int w = tid >> 6;
    const int wr = (w >> 1) * 64, wc = (w & 1) * 32;
    const int fr = lane & 15, fg = lane >> 4;
    const ushort* Wh_ = Whi + (size_t)h * NP * KP;
    const ushort* Wl_ = Wlo + (size_t)h * NP * KP;
    const int rowA = tid >> 2, kc = (tid & 3) * 8;
    f32x4 acc[4][2] = {};
    for (int k0 = 0; k0 < KP; k0 += 32) {
        __syncthreads();
        *(bf16x8*)&Ah[rowA][kc]      = *(const bf16x8*)&Xhi[(size_t)(m0 + rowA) * KP + k0 + kc];
        *(bf16x8*)&Al[rowA][kc]      = *(const bf16x8*)&Xlo[(size_t)(m0 + rowA) * KP + k0 + kc];
        *(bf16x8*)&Ah[rowA + 64][kc] = *(const bf16x8*)&Xhi[(size_t)(m0 + rowA + 64) * KP + k0 + kc];
        *(bf16x8*)&Al[rowA + 64][kc] = *(const bf16x8*)&Xlo[(size_t)(m0 + rowA + 64) * KP + k0 + kc];
        *(bf16x8*)&Bh[rowA][kc]      = *(const bf16x8*)&Wh_[(size_t)(n0 + rowA) * KP + k0 + kc];
        *(bf16x8*)&Bl[rowA][kc]      = *(const bf16x8*)&Wl_[(size_t)(n0 + rowA) * KP + k0 + kc];
        __syncthreads();
        bf16x8 ah[4], al[4], bh[2], bl[2];
#pragma unroll
        for (int i = 0; i < 4; i++) {
            ah[i] = *(const bf16x8*)&Ah[wr + i * 16 + fr][fg * 8];
            al[i] = *(const bf16x8*)&Al[wr + i * 16 + fr][fg * 8];
        }
#pragma unroll
        for (int j = 0; j < 2; j++) {
            bh[j] = *(const bf16x8*)&Bh[wc + j * 16 + fr][fg * 8];
            bl[j] = *(const bf16x8*)&Bl[wc + j * 16 + fr][fg * 8];
        }
#pragma unroll
        for (int i = 0; i < 4; i++)
#pragma unroll
            for (int j = 0; j < 2; j++) {
                acc[i][j] = __builtin_amdgcn_mfma_f32_16x16x32_bf16(ah[i], bh[j], acc[i][j], 0, 0, 0);
                acc[i][j] = __builtin_amdgcn_mfma_f32_16x16x32_bf16(ah[i], bl[j], acc[i][j], 0, 0, 0);
                acc[i][j] = __builtin_amdgcn_mfma_f32_16x16x32_bf16(al[i], bh[j], acc[i][j], 0, 0, 0);
            }
    }
#pragma unroll
    for (int i = 0; i < 4; i++)
#pragma unroll
        for (int j = 0; j < 2; j++)
#pragma unroll
            for (int r = 0; r < 4; r++) {
                int row = m0 + wr + i * 16 + fg * 4 + r;
                int col = n0 + wc + j * 16 + fr;
                if (col < Nreal)
                    Hb[((size_t)h * NNODES + row) * Nreal + col] = acc[i][j][r];
            }
}

// ---------------------------------------------------------------------------
// es[h][n] = dot(H[h][n][:], a_src[h]); ed likewise. One wave per (h,n).
// ---------------------------------------------------------------------------
template<int FOUT>
__global__ __launch_bounds__(256) void scores_kern(const float* __restrict__ Hb,
                                                   const float* __restrict__ Asrc,
                                                   const float* __restrict__ Adst,
                                                   float* __restrict__ es,
                                                   float* __restrict__ ed) {
    int gw = (blockIdx.x * 256 + threadIdx.x) >> 6;
    int lane = threadIdx.x & 63;
    int h = gw / NNODES;
    int n = gw % NNODES;
    const float* hrow = Hb + ((size_t)h * NNODES + n) * FOUT;
    float s = 0.f, d = 0.f;
    for (int o = lane; o < FOUT; o += 64) {
        float v = hrow[o];
        s += v * Asrc[h * FOUT + o];
        d += v * Adst[h * FOUT + o];
    }
#pragma unroll
    for (int sh = 32; sh >= 1; sh >>= 1) {
        s += __shfl_xor(s, sh);
        d += __shfl_xor(d, sh);
    }
    if (lane == 0) { es[h * NNODES + n] = s; ed[h * NNODES + n] = d; }
}

// ---------------------------------------------------------------------------
// Sparse masked-softmax attention aggregate, layers 1/2 (concat over heads).
// Writes fp32 out (optional) and fused bf16 hi/lo split for the next GEMM.
// ---------------------------------------------------------------------------
template<int FOUT, int HEADS, bool RES, bool WF32>
__global__ __launch_bounds__(256) void aggregate_kern(const float* __restrict__ Hb,
                                                      const float* __restrict__ es,
                                                      const float* __restrict__ ed,
                                                      const int* __restrict__ deg,
                                                      const int* __restrict__ nbr,
                                                      const float* __restrict__ residual,
                                                      float* __restrict__ outp,
                                                      ushort* __restrict__ outHi,
                                                      ushort* __restrict__ outLo) {
    int gw = (blockIdx.x * 256 + threadIdx.x) >> 6;
    int lane = threadIdx.x & 63;
    int h = gw / NNODES;
    int n = gw % NNODES;
    int d = deg[n];
    const int* nb = nbr + (size_t)n * MAXD;
    float esn = es[h * NNODES + n];
    float sc[2];
    int nm[2];
    float mx = -INFINITY;
#pragma unroll
    for (int r = 0; r < 2; r++) {
        int j = lane + r * 64;
        int m = (j < d) ? nb[j] : 0;
        nm[r] = m;
        float e = -INFINITY;
        if (j < d) {
            float t = esn + ed[h * NNODES + m];
            e = (t > 0.f) ? t : 0.2f * t;
        }
        sc[r] = e;
        mx = fmaxf(mx, e);
    }
#pragma unroll
    for (int sh = 32; sh >= 1; sh >>= 1) mx = fmaxf(mx, __shfl_xor(mx, sh));
    float sum = 0.f;
#pragma unroll
    for (int r = 0; r < 2; r++) {
        float ex = (sc[r] == -INFINITY) ? 0.f : expf(sc[r] - mx);
        sc[r] = ex;
        sum += ex;
    }
#pragma unroll
    for (int sh = 32; sh >= 1; sh >>= 1) sum += __shfl_xor(sum, sh);
    float inv = 1.f / sum;
    sc[0] *= inv; sc[1] *= inv;
    constexpr int Q = FOUT / 64;
    float acc[Q] = {};
    for (int j = 0; j < d; j++) {
        float a = __shfl(sc[j >> 6], j & 63);
        int m = __shfl(nm[j >> 6], j & 63);
        const float* hrow = Hb + ((size_t)h * NNODES + m) * FOUT;
#pragma unroll
        for (int q = 0; q < Q; q++) acc[q] += a * hrow[lane + q * 64];
    }
#pragma unroll
    for (int q = 0; q < Q; q++) {
        float v = acc[q];
        v = (v > 0.f) ? v : (expf(v) - 1.f);   // ELU
        size_t idx = (size_t)n * (HEADS * FOUT) + (size_t)h * FOUT + lane + q * 64;
        if (RES) v += residual[idx];
        if (WF32) outp[idx] = v;
        ushort hi = f32_to_bf16_rne(v);
        outHi[idx] = hi;
        outLo[idx] = f32_to_bf16_rne(v - bf16_to_f32(hi));
    }
}

// ---------------------------------------------------------------------------
// Layer 3: one block (6 waves) per node; wave h handles head h.
// LDS-reduce head mean, then wave 0 does row log_softmax (121 classes).
// ---------------------------------------------------------------------------
__global__ __launch_bounds__(384) void aggregate3_kern(const float* __restrict__ Hb,
                                                       const float* __restrict__ es,
                                                       const float* __restrict__ ed,
                                                       const int* __restrict__ deg,
                                                       const int* __restrict__ nbr,
                                                       float* __restrict__ outp) {
    constexpr int FOUT = 121;
    __shared__ float red[6][128];
    int n = blockIdx.x;
    int h = threadIdx.x >> 6;       // wave index == head
    int lane = threadIdx.x & 63;
    int d = deg[n];
    const int* nb = nbr + (size_t)n * MAXD;
    float esn = es[h * NNODES + n];
    float sc[2];
    int nm[2];
    float mx = -INFINITY;
#pragma unroll
    for (int r = 0; r < 2; r++) {
        int j = lane + r * 64;
        int m = (j < d) ? nb[j] : 0;
        nm[r] = m;
        float e = -INFINITY;
        if (j < d) {
            float t = esn + ed[h * NNODES + m];
            e = (t > 0.f) ? t : 0.2f * t;
        }
        sc[r] = e;
        mx = fmaxf(mx, e);
    }
#pragma unroll
    for (int sh = 32; sh >= 1; sh >>= 1) mx = fmaxf(mx, __shfl_xor(mx, sh));
    float sum = 0.f;
#pragma unroll
    for (int r = 0; r < 2; r++) {
        float ex = (sc[r] == -INFINITY) ? 0.f : expf(sc[r] - mx);
        sc[r] = ex;
        sum += ex;
    }
#pragma unroll
    for (int sh = 32; sh >= 1; sh >>= 1) sum += __shfl_xor(sum, sh);
    float inv = 1.f / sum;
    sc[0] *= inv; sc[1] *= inv;
    float acc0 = 0.f, acc1 = 0.f;
    for (int j = 0; j < d; j++) {
        float a = __shfl(sc[j >> 6], j & 63);
        int m = __shfl(nm[j >> 6], j & 63);
        const float* hrow = Hb + ((size_t)h * NNODES + m) * FOUT;
        acc0 += a * hrow[lane];
        if (lane < FOUT - 64) acc1 += a * hrow[lane + 64];
    }
    red[h][lane] = acc0;
    red[h][64 + lane] = (lane < FOUT - 64) ? acc1 : 0.f;
    __syncthreads();
    if (h == 0) {
        float l0 = 0.f, l1 = 0.f;
#pragma unroll
        for (int hh = 0; hh < 6; hh++) {
            l0 += red[hh][lane];
            l1 += red[hh][64 + lane];
        }
        l0 *= (1.f / 6.f);
        l1 *= (1.f / 6.f);
        float mx2 = l0;
        if (lane < FOUT - 64) mx2 = fmaxf(mx2, l1);
#pragma unroll
        for (int sh = 32; sh >= 1; sh >>= 1) mx2 = fmaxf(mx2, __shfl_xor(mx2, sh));
        float s = expf(l0 - mx2) + ((lane < FOUT - 64) ? expf(l1 - mx2) : 0.f);
#pragma unroll
        for (int sh = 32; sh >= 1; sh >>= 1) s += __shfl_xor(s, sh);
        float lse = logf(s);
        outp[(size_t)n * FOUT + lane] = l0 - mx2 - lse;
        if (lane < FOUT - 64) outp[(size_t)n * FOUT + 64 + lane] = l1 - mx2 - lse;
    }
}

// ---------------------------------------------------------------------------
extern "C" void kernel_launch(void* const* d_in, const int* in_sizes, int n_in,
                              void* d_out, int out_size, void* d_ws, size_t ws_size,
                              hipStream_t stream) {
    const float* x   = (const float*)d_in[0];
    const int*   adj = (const int*)d_in[1];
    const float* W1  = (const float*)d_in[2];
    const float* a1s = (const float*)d_in[3];
    const float* a1d = (const float*)d_in[4];
    const float* W2  = (const float*)d_in[5];
    const float* a2s = (const float*)d_in[6];
    const float* a2d = (const float*)d_in[7];
    const float* W3  = (const float*)d_in[8];
    const float* a3s = (const float*)d_in[9];
    const float* a3d = (const float*)d_in[10];
    float* outp = (float*)d_out;

    char* w = (char*)d_ws;
    int* deg = (int*)w;      w += (size_t)NNODES * sizeof(int);
    int* nbr = (int*)w;      w += (size_t)NNODES * MAXD * sizeof(int);
    float* hbuf = (float*)w; w += (size_t)4 * NNODES * 256 * sizeof(float);  // 16 MB (also fits 6*N*121)
    float* es = (float*)w;   w += (size_t)6 * NNODES * sizeof(float);
    float* ed = (float*)w;   w += (size_t)6 * NNODES * sizeof(float);
    float* x1 = (float*)w;   w += (size_t)NNODES * 1024 * sizeof(float);
    ushort* Xhi = (ushort*)w; w += (size_t)NNODES * 1024 * sizeof(ushort);   // shared for x/x1/x2
    ushort* Xlo = (ushort*)w; w += (size_t)NNODES * 1024 * sizeof(ushort);
    ushort* W1h = (ushort*)w; w += (size_t)4 * 256 * 64 * sizeof(ushort);
    ushort* W1l = (ushort*)w; w += (size_t)4 * 256 * 64 * sizeof(ushort);
    ushort* W2h = (ushort*)w; w += (size_t)4 * 256 * 1024 * sizeof(ushort);
    ushort* W2l = (ushort*)w; w += (size_t)4 * 256 * 1024 * sizeof(ushort);
    ushort* W3h = (ushort*)w; w += (size_t)6 * 128 * 1024 * sizeof(ushort);
    ushort* W3l = (ushort*)w; w += (size_t)6 * 128 * 1024 * sizeof(ushort);

    build_csr<<<NNODES, 256, 0, stream>>>(adj, deg, nbr);

    // Weight transpose+split (independent of layer outputs)
    wsplit<<<dim3(2, 8, 4), 256, 0, stream>>>(W1, W1h, W1l, 50, 64, 256, 256);
    wsplit<<<dim3(32, 8, 4), 256, 0, stream>>>(W2, W2h, W2l, 1024, 1024, 256, 256);
    wsplit<<<dim3(32, 4, 6), 256, 0, stream>>>(W3, W3h, W3l, 1024, 1024, 121, 128);

    // ---- Layer 1: x[4096,50] -> x1[4096,1024]
    xsplit<<<1024, 256, 0, stream>>>(x, Xhi, Xlo, NNODES, 50, 6);
    gemm_mfma<<<dim3(32, 4, 4), 256, 0, stream>>>(Xhi, Xlo, W1h, W1l, hbuf, 64, 256, 256);
    scores_kern<256><<<4 * NNODES / 4, 256, 0, stream>>>(hbuf, a1s, a1d, es, ed);
    aggregate_kern<256, 4, false, true><<<4 * NNODES / 4, 256, 0, stream>>>(
        hbuf, es, ed, deg, nbr, nullptr, x1, Xhi, Xlo);

    // ---- Layer 2: x1 -> x2 = ELU(gat(x1)) + x1   (split written directly)
    gemm_mfma<<<dim3(32, 4, 4), 256, 0, stream>>>(Xhi, Xlo, W2h, W2l, hbuf, 1024, 256, 256);
    scores_kern<256><<<4 * NNODES / 4, 256, 0, stream>>>(hbuf, a2s, a2d, es, ed);
    aggregate_kern<256, 4, true, false><<<4 * NNODES / 4, 256, 0, stream>>>(
        hbuf, es, ed, deg, nbr, x1, nullptr, Xhi, Xlo);

    // ---- Layer 3: x2 -> out = log_softmax(mean_h gat(x2))
    gemm_mfma<<<dim3(32, 2, 6), 256, 0, stream>>>(Xhi, Xlo, W3h, W3l, hbuf, 1024, 128, 121);
    scores_kern<121><<<6 * NNODES / 4, 256, 0, stream>>>(hbuf, a3s, a3d, es, ed);
    aggregate3_kern<<<NNODES, 384, 0, stream>>>(hbuf, es, ed, deg, nbr, outp);
}

// Round 4
// 228.699 us; speedup vs baseline: 2.5803x; 1.0763x over previous
//
#include <hip/hip_runtime.h>
#include <hip/hip_bf16.h>
#include <math.h>

#define NNODES 4096
#define MAXD 128

typedef __attribute__((ext_vector_type(8))) short bf16x8;
typedef __attribute__((ext_vector_type(4))) float f32x4;

__device__ inline ushort f32_to_bf16_rne(float f) {
    uint32_t u = __float_as_uint(f);
    u += 0x7FFFu + ((u >> 16) & 1u);
    return (ushort)(u >> 16);
}
__device__ inline float bf16_to_f32(ushort h) {
    return __uint_as_float((uint32_t)h << 16);
}

// ---------------------------------------------------------------------------
// CSR build: one block per row, deterministic ordered compaction.
// ---------------------------------------------------------------------------
__global__ __launch_bounds__(256) void build_csr(const int* __restrict__ adj,
                                                 int* __restrict__ deg,
                                                 int* __restrict__ nbr) {
    int n = blockIdx.x;
    const int* row = adj + (size_t)n * NNODES;
    int t = threadIdx.x;
    __shared__ int cnts[256];
    int c0 = t * 16;
    int cnt = 0;
#pragma unroll
    for (int i = 0; i < 16; i++) cnt += (row[c0 + i] != 0) ? 1 : 0;
    cnts[t] = cnt;
    __syncthreads();
    if (t == 0) {
        int s = 0;
        for (int i = 0; i < 256; i++) { int c = cnts[i]; cnts[i] = s; s += c; }
        deg[n] = (s < MAXD) ? s : MAXD;
    }
    __syncthreads();
    int o = cnts[t];
    int* outr = nbr + (size_t)n * MAXD;
#pragma unroll
    for (int i = 0; i < 16; i++) {
        if (row[c0 + i] != 0) {
            if (o < MAXD) outr[o] = c0 + i;
            o++;
        }
    }
}

// ---------------------------------------------------------------------------
// Split X [M][K] fp32 -> hi/lo bf16 [M][KP] (zero-pad k>=K). KP power of 2.
// ---------------------------------------------------------------------------
__global__ __launch_bounds__(256) void xsplit(const float* __restrict__ X,
                                              ushort* __restrict__ Xhi,
                                              ushort* __restrict__ Xlo,
                                              int M, int K, int KP_log2) {
    int KP = 1 << KP_log2;
    int total = M << KP_log2;
    for (int i = blockIdx.x * 256 + threadIdx.x; i < total; i += gridDim.x * 256) {
        int k = i & (KP - 1);
        int m = i >> KP_log2;
        float v = (k < K) ? X[(size_t)m * K + k] : 0.f;
        ushort hi = f32_to_bf16_rne(v);
        float hf = bf16_to_f32(hi);
        Xhi[i] = hi;
        Xlo[i] = f32_to_bf16_rne(v - hf);
    }
}

// ---------------------------------------------------------------------------
// Transpose-split W [H][K][N] fp32 -> Wt hi/lo [H][NP][KP] bf16, zero-padded.
// ---------------------------------------------------------------------------
__global__ __launch_bounds__(256) void wsplit(const float* __restrict__ W,
                                              ushort* __restrict__ Whi,
                                              ushort* __restrict__ Wlo,
                                              int K, int KP, int N, int NP) {
    __shared__ float tile[32][33];
    int h = blockIdx.z;
    int k0 = blockIdx.x * 32, n0 = blockIdx.y * 32;
    int tid = threadIdx.x;
    const float* Wh_ = W + (size_t)h * K * N;
#pragma unroll
    for (int r = 0; r < 4; r++) {
        int kl = (tid >> 5) + r * 8;
        int nl = tid & 31;
        int k = k0 + kl, n = n0 + nl;
        tile[kl][nl] = (k < K && n < N) ? Wh_[(size_t)k * N + n] : 0.f;
    }
    __syncthreads();
#pragma unroll
    for (int r = 0; r < 4; r++) {
        int nl = (tid >> 5) + r * 8;
        int kl = tid & 31;
        float v = tile[kl][nl];
        ushort hi = f32_to_bf16_rne(v);
        float hf = bf16_to_f32(hi);
        ushort lo = f32_to_bf16_rne(v - hf);
        size_t o = ((size_t)h * NP + n0 + nl) * KP + k0 + kl;
        Whi[o] = hi;
        Wlo[o] = lo;
    }
}

// ---------------------------------------------------------------------------
// Split-precision bf16 MFMA GEMM, XCD-pinned by head via 1D grid remap.
// Block tile 128x64 (4 waves, 64x32 wave tiles), K-step 32, 16x16x32 MFMA.
// ---------------------------------------------------------------------------
__global__ __launch_bounds__(256) void gemm_mfma(const ushort* __restrict__ Xhi,
                                                 const ushort* __restrict__ Xlo,
                                                 const ushort* __restrict__ Whi,
                                                 const ushort* __restrict__ Wlo,
                                                 float* __restrict__ Hb,
                                                 int KP, int NP, int Nreal, int nby) {
    __shared__ ushort Ah[128][40], Al[128][40], Bh[64][40], Bl[64][40];
    // XCD-pinned decode: b%8 -> XCD; sequential g walks heads in order.
    int b = blockIdx.x;
    int perx = gridDim.x >> 3;
    int g = (b & 7) * perx + (b >> 3);
    int per_head = 32 * nby;
    int h = g / per_head;
    int r0 = g - h * per_head;
    const int m0 = (r0 / nby) * 128;
    const int n0 = (r0 % nby) * 64;
    const int tid = threadIdx.x;
    const int lane = tid & 63;
    const int w = tid >> 6;
    const int wr = (w >> 1) * 64, wc = (w & 1) * 32;
    const int fr = lane & 15, fg = lane >> 4;
    const ushort* Wh_ = Whi + (size_t)h * NP * KP;
    const ushort* Wl_ = Wlo + (size_t)h * NP * KP;
    const int rowA = tid >> 2, kc = (tid & 3) * 8;
    f32x4 acc[4][2] = {};
    for (int k0 = 0; k0 < KP; k0 += 32) {
        __syncthreads();
        *(bf16x8*)&Ah[rowA][kc]      = *(const bf16x8*)&Xhi[(size_t)(m0 + rowA) * KP + k0 + kc];
        *(bf16x8*)&Al[rowA][kc]      = *(const bf16x8*)&Xlo[(size_t)(m0 + rowA) * KP + k0 + kc];
        *(bf16x8*)&Ah[rowA + 64][kc] = *(const bf16x8*)&Xhi[(size_t)(m0 + rowA + 64) * KP + k0 + kc];
        *(bf16x8*)&Al[rowA + 64][kc] = *(const bf16x8*)&Xlo[(size_t)(m0 + rowA + 64) * KP + k0 + kc];
        *(bf16x8*)&Bh[rowA][kc]      = *(const bf16x8*)&Wh_[(size_t)(n0 + rowA) * KP + k0 + kc];
        *(bf16x8*)&Bl[rowA][kc]      = *(const bf16x8*)&Wl_[(size_t)(n0 + rowA) * KP + k0 + kc];
        __syncthreads();
        bf16x8 ah[4], al[4], bh[2], bl[2];
#pragma unroll
        for (int i = 0; i < 4; i++) {
            ah[i] = *(const bf16x8*)&Ah[wr + i * 16 + fr][fg * 8];
            al[i] = *(const bf16x8*)&Al[wr + i * 16 + fr][fg * 8];
        }
#pragma unroll
        for (int j = 0; j < 2; j++) {
            bh[j] = *(const bf16x8*)&Bh[wc + j * 16 + fr][fg * 8];
            bl[j] = *(const bf16x8*)&Bl[wc + j * 16 + fr][fg * 8];
        }
#pragma unroll
        for (int i = 0; i < 4; i++)
#pragma unroll
            for (int j = 0; j < 2; j++) {
                acc[i][j] = __builtin_amdgcn_mfma_f32_16x16x32_bf16(ah[i], bh[j], acc[i][j], 0, 0, 0);
                acc[i][j] = __builtin_amdgcn_mfma_f32_16x16x32_bf16(ah[i], bl[j], acc[i][j], 0, 0, 0);
                acc[i][j] = __builtin_amdgcn_mfma_f32_16x16x32_bf16(al[i], bh[j], acc[i][j], 0, 0, 0);
            }
    }
#pragma unroll
    for (int i = 0; i < 4; i++)
#pragma unroll
        for (int j = 0; j < 2; j++)
#pragma unroll
            for (int r = 0; r < 4; r++) {
                int row = m0 + wr + i * 16 + fg * 4 + r;
                int col = n0 + wc + j * 16 + fr;
                if (col < Nreal)
                    Hb[((size_t)h * NNODES + row) * Nreal + col] = acc[i][j][r];
            }
}

// ---------------------------------------------------------------------------
// es[h][n] = dot(H[h][n][:], a_src[h]); ed likewise. One wave per (h,n).
// XCD-pinned by head (NCH = node-chunks per head = NNODES/4).
// ---------------------------------------------------------------------------
template<int FOUT, int HEADS>
__global__ __launch_bounds__(256) void scores_kern(const float* __restrict__ Hb,
                                                   const float* __restrict__ Asrc,
                                                   const float* __restrict__ Adst,
                                                   float* __restrict__ es,
                                                   float* __restrict__ ed) {
    int b = blockIdx.x;
    int g = (b & 7) * ((HEADS * NNODES / 4) / 8) + (b >> 3);
    int h = g / (NNODES / 4);
    int n = (g % (NNODES / 4)) * 4 + (threadIdx.x >> 6);
    int lane = threadIdx.x & 63;
    const float* hrow = Hb + ((size_t)h * NNODES + n) * FOUT;
    float s = 0.f, d = 0.f;
    for (int o = lane; o < FOUT; o += 64) {
        float v = hrow[o];
        s += v * Asrc[h * FOUT + o];
        d += v * Adst[h * FOUT + o];
    }
#pragma unroll
    for (int sh = 32; sh >= 1; sh >>= 1) {
        s += __shfl_xor(s, sh);
        d += __shfl_xor(d, sh);
    }
    if (lane == 0) { es[h * NNODES + n] = s; ed[h * NNODES + n] = d; }
}

// ---------------------------------------------------------------------------
// Sparse masked-softmax attention aggregate, layers 1/2. XCD-pinned by head.
// Writes fp32 out (optional) and fused bf16 hi/lo split for the next GEMM.
// ---------------------------------------------------------------------------
template<int FOUT, int HEADS, bool RES, bool WF32>
__global__ __launch_bounds__(256) void aggregate_kern(const float* __restrict__ Hb,
                                                      const float* __restrict__ es,
                                                      const float* __restrict__ ed,
                                                      const int* __restrict__ deg,
                                                      const int* __restrict__ nbr,
                                                      const float* __restrict__ residual,
                                                      float* __restrict__ outp,
                                                      ushort* __restrict__ outHi,
                                                      ushort* __restrict__ outLo) {
    int b = blockIdx.x;
    int g = (b & 7) * ((HEADS * NNODES / 4) / 8) + (b >> 3);
    int h = g / (NNODES / 4);
    int n = (g % (NNODES / 4)) * 4 + (threadIdx.x >> 6);
    int lane = threadIdx.x & 63;
    int d = deg[n];
    const int* nb = nbr + (size_t)n * MAXD;
    float esn = es[h * NNODES + n];
    float sc[2];
    int nm[2];
    float mx = -INFINITY;
#pragma unroll
    for (int r = 0; r < 2; r++) {
        int j = lane + r * 64;
        int m = (j < d) ? nb[j] : 0;
        nm[r] = m;
        float e = -INFINITY;
        if (j < d) {
            float t = esn + ed[h * NNODES + m];
            e = (t > 0.f) ? t : 0.2f * t;
        }
        sc[r] = e;
        mx = fmaxf(mx, e);
    }
#pragma unroll
    for (int sh = 32; sh >= 1; sh >>= 1) mx = fmaxf(mx, __shfl_xor(mx, sh));
    float sum = 0.f;
#pragma unroll
    for (int r = 0; r < 2; r++) {
        float ex = (sc[r] == -INFINITY) ? 0.f : expf(sc[r] - mx);
        sc[r] = ex;
        sum += ex;
    }
#pragma unroll
    for (int sh = 32; sh >= 1; sh >>= 1) sum += __shfl_xor(sum, sh);
    float inv = 1.f / sum;
    sc[0] *= inv; sc[1] *= inv;
    constexpr int Q = FOUT / 64;
    float acc[Q] = {};
    for (int j = 0; j < d; j++) {
        float a = __shfl(sc[j >> 6], j & 63);
        int m = __shfl(nm[j >> 6], j & 63);
        const float* hrow = Hb + ((size_t)h * NNODES + m) * FOUT;
#pragma unroll
        for (int q = 0; q < Q; q++) acc[q] += a * hrow[lane + q * 64];
    }
#pragma unroll
    for (int q = 0; q < Q; q++) {
        float v = acc[q];
        v = (v > 0.f) ? v : (expf(v) - 1.f);   // ELU
        size_t idx = (size_t)n * (HEADS * FOUT) + (size_t)h * FOUT + lane + q * 64;
        if (RES) v += residual[idx];
        if (WF32) outp[idx] = v;
        ushort hi = f32_to_bf16_rne(v);
        outHi[idx] = hi;
        outLo[idx] = f32_to_bf16_rne(v - bf16_to_f32(hi));
    }
}

// ---------------------------------------------------------------------------
// Layer 3a: per-(h,n) pinned aggregate -> agg[h][n][128] (fp32).
// ---------------------------------------------------------------------------
__global__ __launch_bounds__(256) void aggregate3a_kern(const float* __restrict__ Hb,
                                                        const float* __restrict__ es,
                                                        const float* __restrict__ ed,
                                                        const int* __restrict__ deg,
                                                        const int* __restrict__ nbr,
                                                        float* __restrict__ agg) {
    constexpr int FOUT = 121, HEADS = 6;
    int b = blockIdx.x;   // 6144 blocks
    int g = (b & 7) * ((HEADS * NNODES / 4) / 8) + (b >> 3);
    int h = g / (NNODES / 4);
    int n = (g % (NNODES / 4)) * 4 + (threadIdx.x >> 6);
    int lane = threadIdx.x & 63;
    int d = deg[n];
    const int* nb = nbr + (size_t)n * MAXD;
    float esn = es[h * NNODES + n];
    float sc[2];
    int nm[2];
    float mx = -INFINITY;
#pragma unroll
    for (int r = 0; r < 2; r++) {
        int j = lane + r * 64;
        int m = (j < d) ? nb[j] : 0;
        nm[r] = m;
        float e = -INFINITY;
        if (j < d) {
            float t = esn + ed[h * NNODES + m];
            e = (t > 0.f) ? t : 0.2f * t;
        }
        sc[r] = e;
        mx = fmaxf(mx, e);
    }
#pragma unroll
    for (int sh = 32; sh >= 1; sh >>= 1) mx = fmaxf(mx, __shfl_xor(mx, sh));
    float sum = 0.f;
#pragma unroll
    for (int r = 0; r < 2; r++) {
        float ex = (sc[r] == -INFINITY) ? 0.f : expf(sc[r] - mx);
        sc[r] = ex;
        sum += ex;
    }
#pragma unroll
    for (int sh = 32; sh >= 1; sh >>= 1) sum += __shfl_xor(sum, sh);
    float inv = 1.f / sum;
    sc[0] *= inv; sc[1] *= inv;
    float acc0 = 0.f, acc1 = 0.f;
    for (int j = 0; j < d; j++) {
        float a = __shfl(sc[j >> 6], j & 63);
        int m = __shfl(nm[j >> 6], j & 63);
        const float* hrow = Hb + ((size_t)h * NNODES + m) * FOUT;
        acc0 += a * hrow[lane];
        if (lane < FOUT - 64) acc1 += a * hrow[lane + 64];
    }
    size_t base = ((size_t)h * NNODES + n) * 128;
    agg[base + lane] = acc0;
    agg[base + 64 + lane] = (lane < FOUT - 64) ? acc1 : 0.f;
}

// ---------------------------------------------------------------------------
// Layer 3b: mean over 6 heads + row log_softmax (121 classes). 1 wave/node.
// ---------------------------------------------------------------------------
__global__ __launch_bounds__(256) void reduce3_kern(const float* __restrict__ agg,
                                                    float* __restrict__ outp) {
    constexpr int FOUT = 121;
    int n = blockIdx.x * 4 + (threadIdx.x >> 6);
    int lane = threadIdx.x & 63;
    float l0 = 0.f, l1 = 0.f;
#pragma unroll
    for (int h = 0; h < 6; h++) {
        size_t base = ((size_t)h * NNODES + n) * 128;
        l0 += agg[base + lane];
        l1 += agg[base + 64 + lane];
    }
    l0 *= (1.f / 6.f);
    l1 *= (1.f / 6.f);
    float mx = l0;
    if (lane < FOUT - 64) mx = fmaxf(mx, l1);
#pragma unroll
    for (int sh = 32; sh >= 1; sh >>= 1) mx = fmaxf(mx, __shfl_xor(mx, sh));
    float s = expf(l0 - mx) + ((lane < FOUT - 64) ? expf(l1 - mx) : 0.f);
#pragma unroll
    for (int sh = 32; sh >= 1; sh >>= 1) s += __shfl_xor(s, sh);
    float lse = logf(s);
    outp[(size_t)n * FOUT + lane] = l0 - mx - lse;
    if (lane < FOUT - 64) outp[(size_t)n * FOUT + 64 + lane] = l1 - mx - lse;
}

// ---------------------------------------------------------------------------
extern "C" void kernel_launch(void* const* d_in, const int* in_sizes, int n_in,
                              void* d_out, int out_size, void* d_ws, size_t ws_size,
                              hipStream_t stream) {
    const float* x   = (const float*)d_in[0];
    const int*   adj = (const int*)d_in[1];
    const float* W1  = (const float*)d_in[2];
    const float* a1s = (const float*)d_in[3];
    const float* a1d = (const float*)d_in[4];
    const float* W2  = (const float*)d_in[5];
    const float* a2s = (const float*)d_in[6];
    const float* a2d = (const float*)d_in[7];
    const float* W3  = (const float*)d_in[8];
    const float* a3s = (const float*)d_in[9];
    const float* a3d = (const float*)d_in[10];
    float* outp = (float*)d_out;

    char* w = (char*)d_ws;
    int* deg = (int*)w;      w += (size_t)NNODES * sizeof(int);
    int* nbr = (int*)w;      w += (size_t)NNODES * MAXD * sizeof(int);
    float* hbuf = (float*)w; w += (size_t)4 * NNODES * 256 * sizeof(float);  // 16 MB (also fits 6*N*121)
    float* es = (float*)w;   w += (size_t)6 * NNODES * sizeof(float);
    float* ed = (float*)w;   w += (size_t)6 * NNODES * sizeof(float);
    float* x1 = (float*)w;   w += (size_t)NNODES * 1024 * sizeof(float);
    ushort* Xhi = (ushort*)w; w += (size_t)NNODES * 1024 * sizeof(ushort);   // shared for x/x1/x2
    ushort* Xlo = (ushort*)w; w += (size_t)NNODES * 1024 * sizeof(ushort);
    ushort* W1h = (ushort*)w; w += (size_t)4 * 256 * 64 * sizeof(ushort);
    ushort* W1l = (ushort*)w; w += (size_t)4 * 256 * 64 * sizeof(ushort);
    ushort* W2h = (ushort*)w; w += (size_t)4 * 256 * 1024 * sizeof(ushort);
    ushort* W2l = (ushort*)w; w += (size_t)4 * 256 * 1024 * sizeof(ushort);
    ushort* W3h = (ushort*)w; w += (size_t)6 * 128 * 1024 * sizeof(ushort);
    ushort* W3l = (ushort*)w; w += (size_t)6 * 128 * 1024 * sizeof(ushort);
    // agg[6][4096][128] fp32 (12.6 MB) aliases Xhi/Xlo (16 MB): Xhi/Xlo are
    // dead after the L3 GEMM and fully rewritten every call before reuse.
    float* agg = (float*)Xhi;

    build_csr<<<NNODES, 256, 0, stream>>>(adj, deg, nbr);

    // Weight transpose+split (independent of layer outputs)
    wsplit<<<dim3(2, 8, 4), 256, 0, stream>>>(W1, W1h, W1l, 50, 64, 256, 256);
    wsplit<<<dim3(32, 8, 4), 256, 0, stream>>>(W2, W2h, W2l, 1024, 1024, 256, 256);
    wsplit<<<dim3(32, 4, 6), 256, 0, stream>>>(W3, W3h, W3l, 1024, 1024, 121, 128);

    // ---- Layer 1: x[4096,50] -> x1[4096,1024]
    xsplit<<<1024, 256, 0, stream>>>(x, Xhi, Xlo, NNODES, 50, 6);
    gemm_mfma<<<32 * 4 * 4, 256, 0, stream>>>(Xhi, Xlo, W1h, W1l, hbuf, 64, 256, 256, 4);
    scores_kern<256, 4><<<4 * NNODES / 4, 256, 0, stream>>>(hbuf, a1s, a1d, es, ed);
    aggregate_kern<256, 4, false, true><<<4 * NNODES / 4, 256, 0, stream>>>(
        hbuf, es, ed, deg, nbr, nullptr, x1, Xhi, Xlo);

    // ---- Layer 2: x1 -> x2 = ELU(gat(x1)) + x1   (split written directly)
    gemm_mfma<<<32 * 4 * 4, 256, 0, stream>>>(Xhi, Xlo, W2h, W2l, hbuf, 1024, 256, 256, 4);
    scores_kern<256, 4><<<4 * NNODES / 4, 256, 0, stream>>>(hbuf, a2s, a2d, es, ed);
    aggregate_kern<256, 4, true, false><<<4 * NNODES / 4, 256, 0, stream>>>(
        hbuf, es, ed, deg, nbr, x1, nullptr, Xhi, Xlo);

    // ---- Layer 3: x2 -> out = log_softmax(mean_h gat(x2))
    gemm_mfma<<<32 * 2 * 6, 256, 0, stream>>>(Xhi, Xlo, W3h, W3l, hbuf, 1024, 128, 121, 2);
    scores_kern<121, 6><<<6 * NNODES / 4, 256, 0, stream>>>(hbuf, a3s, a3d, es, ed);
    aggregate3a_kern<<<6 * NNODES / 4, 256, 0, stream>>>(hbuf, es, ed, deg, nbr, agg);
    reduce3_kern<<<NNODES / 4, 256, 0, stream>>>(agg, outp);
}

// Round 5
// 212.434 us; speedup vs baseline: 2.7779x; 1.0766x over previous
//
#include <hip/hip_runtime.h>
#include <hip/hip_bf16.h>
#include <math.h>

#define NNODES 4096
#define MAXD 128

typedef __attribute__((ext_vector_type(8))) short bf16x8;
typedef __attribute__((ext_vector_type(4))) float f32x4;
typedef __attribute__((ext_vector_type(2))) float f32x2;
typedef __attribute__((ext_vector_type(4))) ushort u16x4;

__device__ inline ushort f32_to_bf16_rne(float f) {
    uint32_t u = __float_as_uint(f);
    u += 0x7FFFu + ((u >> 16) & 1u);
    return (ushort)(u >> 16);
}
__device__ inline float bf16_to_f32(ushort h) {
    return __uint_as_float((uint32_t)h << 16);
}

// ---------------------------------------------------------------------------
// CSR build: one block per row, deterministic ordered compaction. int4 loads.
// ---------------------------------------------------------------------------
__global__ __launch_bounds__(256) void build_csr(const int* __restrict__ adj,
                                                 int* __restrict__ deg,
                                                 int* __restrict__ nbr) {
    int n = blockIdx.x;
    const int* row = adj + (size_t)n * NNODES;
    int t = threadIdx.x;
    __shared__ int cnts[256];
    int c0 = t * 16;
    int vals[16];
    const int4* r4 = (const int4*)(row + c0);
#pragma unroll
    for (int i = 0; i < 4; i++) {
        int4 v = r4[i];
        vals[4 * i] = v.x; vals[4 * i + 1] = v.y; vals[4 * i + 2] = v.z; vals[4 * i + 3] = v.w;
    }
    int cnt = 0;
#pragma unroll
    for (int i = 0; i < 16; i++) cnt += (vals[i] != 0) ? 1 : 0;
    cnts[t] = cnt;
    __syncthreads();
    if (t == 0) {
        int s = 0;
        for (int i = 0; i < 256; i++) { int c = cnts[i]; cnts[i] = s; s += c; }
        deg[n] = (s < MAXD) ? s : MAXD;
    }
    __syncthreads();
    int o = cnts[t];
    int* outr = nbr + (size_t)n * MAXD;
#pragma unroll
    for (int i = 0; i < 16; i++) {
        if (vals[i] != 0) {
            if (o < MAXD) outr[o] = c0 + i;
            o++;
        }
    }
}

// ---------------------------------------------------------------------------
// Split X [M][K] fp32 -> hi/lo bf16 [M][KP] (zero-pad k>=K). KP power of 2.
// ---------------------------------------------------------------------------
__global__ __launch_bounds__(256) void xsplit(const float* __restrict__ X,
                                              ushort* __restrict__ Xhi,
                                              ushort* __restrict__ Xlo,
                                              int M, int K, int KP_log2) {
    int KP = 1 << KP_log2;
    int total = M << KP_log2;
    for (int i = blockIdx.x * 256 + threadIdx.x; i < total; i += gridDim.x * 256) {
        int k = i & (KP - 1);
        int m = i >> KP_log2;
        float v = (k < K) ? X[(size_t)m * K + k] : 0.f;
        ushort hi = f32_to_bf16_rne(v);
        float hf = bf16_to_f32(hi);
        Xhi[i] = hi;
        Xlo[i] = f32_to_bf16_rne(v - hf);
    }
}

// ---------------------------------------------------------------------------
// Transpose-split W [H][K][N] fp32 -> Wt hi/lo [H][NP][KP] bf16, zero-padded.
// ---------------------------------------------------------------------------
__global__ __launch_bounds__(256) void wsplit(const float* __restrict__ W,
                                              ushort* __restrict__ Whi,
                                              ushort* __restrict__ Wlo,
                                              int K, int KP, int N, int NP) {
    __shared__ float tile[32][33];
    int h = blockIdx.z;
    int k0 = blockIdx.x * 32, n0 = blockIdx.y * 32;
    int tid = threadIdx.x;
    const float* Wh_ = W + (size_t)h * K * N;
#pragma unroll
    for (int r = 0; r < 4; r++) {
        int kl = (tid >> 5) + r * 8;
        int nl = tid & 31;
        int k = k0 + kl, n = n0 + nl;
        tile[kl][nl] = (k < K && n < N) ? Wh_[(size_t)k * N + n] : 0.f;
    }
    __syncthreads();
#pragma unroll
    for (int r = 0; r < 4; r++) {
        int nl = (tid >> 5) + r * 8;
        int kl = tid & 31;
        float v = tile[kl][nl];
        ushort hi = f32_to_bf16_rne(v);
        float hf = bf16_to_f32(hi);
        ushort lo = f32_to_bf16_rne(v - hf);
        size_t o = ((size_t)h * NP + n0 + nl) * KP + k0 + kl;
        Whi[o] = hi;
        Wlo[o] = lo;
    }
}

// ---------------------------------------------------------------------------
// Split-precision bf16 MFMA GEMM, XCD-pinned by head via 1D grid remap.
// Block tile 128x64 (4 waves, 64x32 wave tiles), BK=64, 16x16x32 MFMA.
// Register-prefetch staging: next K-tile global loads issue before MFMA phase.
// ---------------------------------------------------------------------------
__global__ __launch_bounds__(256) void gemm_mfma(const ushort* __restrict__ Xhi,
                                                 const ushort* __restrict__ Xlo,
                                                 const ushort* __restrict__ Whi,
                                                 const ushort* __restrict__ Wlo,
                                                 float* __restrict__ Hb,
                                                 int KP, int NP, int Nstride, int nby) {
    __shared__ ushort Ah[128][72], Al[128][72], Bh[64][72], Bl[64][72];
    int b = blockIdx.x;
    int perx = gridDim.x >> 3;
    int g = (b & 7) * perx + (b >> 3);
    int per_head = 32 * nby;
    int h = g / per_head;
    int r0 = g - h * per_head;
    const int m0 = (r0 / nby) * 128;
    const int n0 = (r0 % nby) * 64;
    const int tid = threadIdx.x;
    const int lane = tid & 63;
    const int w = tid >> 6;
    const int wr = (w >> 1) * 64, wc = (w & 1) * 32;
    const int fr = lane & 15, fg = lane >> 4;
    const ushort* Wh_ = Whi + (size_t)h * NP * KP;
    const ushort* Wl_ = Wlo + (size_t)h * NP * KP;
    const int sr = tid >> 3;            // 0..31
    const int sc = (tid & 7) * 8;       // 0..56 (ushort col)
    bf16x8 pa_h[4], pa_l[4], pb_h[2], pb_l[2];
    auto LOADG = [&](int K0) {
#pragma unroll
        for (int i = 0; i < 4; i++) {
            int r = sr + 32 * i;
            pa_h[i] = *(const bf16x8*)&Xhi[(size_t)(m0 + r) * KP + K0 + sc];
            pa_l[i] = *(const bf16x8*)&Xlo[(size_t)(m0 + r) * KP + K0 + sc];
        }
#pragma unroll
        for (int i = 0; i < 2; i++) {
            int r = sr + 32 * i;
            pb_h[i] = *(const bf16x8*)&Wh_[(size_t)(n0 + r) * KP + K0 + sc];
            pb_l[i] = *(const bf16x8*)&Wl_[(size_t)(n0 + r) * KP + K0 + sc];
        }
    };
    LOADG(0);
    f32x4 acc[4][2] = {};
    for (int k0 = 0; k0 < KP; k0 += 64) {
#pragma unroll
        for (int i = 0; i < 4; i++) {
            int r = sr + 32 * i;
            *(bf16x8*)&Ah[r][sc] = pa_h[i];
            *(bf16x8*)&Al[r][sc] = pa_l[i];
        }
#pragma unroll
        for (int i = 0; i < 2; i++) {
            int r = sr + 32 * i;
            *(bf16x8*)&Bh[r][sc] = pb_h[i];
            *(bf16x8*)&Bl[r][sc] = pb_l[i];
        }
        __syncthreads();
        if (k0 + 64 < KP) LOADG(k0 + 64);
#pragma unroll
        for (int ks = 0; ks < 2; ks++) {
            bf16x8 ah[4], al[4], bh[2], bl[2];
#pragma unroll
            for (int i = 0; i < 4; i++) {
                ah[i] = *(const bf16x8*)&Ah[wr + i * 16 + fr][ks * 32 + fg * 8];
                al[i] = *(const bf16x8*)&Al[wr + i * 16 + fr][ks * 32 + fg * 8];
            }
#pragma unroll
            for (int j = 0; j < 2; j++) {
                bh[j] = *(const bf16x8*)&Bh[wc + j * 16 + fr][ks * 32 + fg * 8];
                bl[j] = *(const bf16x8*)&Bl[wc + j * 16 + fr][ks * 32 + fg * 8];
            }
#pragma unroll
            for (int i = 0; i < 4; i++)
#pragma unroll
                for (int j = 0; j < 2; j++) {
                    acc[i][j] = __builtin_amdgcn_mfma_f32_16x16x32_bf16(ah[i], bh[j], acc[i][j], 0, 0, 0);
                    acc[i][j] = __builtin_amdgcn_mfma_f32_16x16x32_bf16(ah[i], bl[j], acc[i][j], 0, 0, 0);
                    acc[i][j] = __builtin_amdgcn_mfma_f32_16x16x32_bf16(al[i], bh[j], acc[i][j], 0, 0, 0);
                }
        }
        __syncthreads();
    }
#pragma unroll
    for (int i = 0; i < 4; i++)
#pragma unroll
        for (int j = 0; j < 2; j++)
#pragma unroll
            for (int r = 0; r < 4; r++) {
                int row = m0 + wr + i * 16 + fg * 4 + r;
                int col = n0 + wc + j * 16 + fr;
                Hb[((size_t)h * NNODES + row) * Nstride + col] = acc[i][j][r];
            }
}

// ---------------------------------------------------------------------------
// es[h][n] = dot(H[h][n][:], a_src[h]); ed likewise. One wave per (h,n).
// Vector path for FOUT=256; scalar path otherwise (stride-parameterized).
// ---------------------------------------------------------------------------
template<int FOUT, int STRIDE, int HEADS>
__global__ __launch_bounds__(256) void scores_kern(const float* __restrict__ Hb,
                                                   const float* __restrict__ Asrc,
                                                   const float* __restrict__ Adst,
                                                   float* __restrict__ es,
                                                   float* __restrict__ ed) {
    int b = blockIdx.x;
    int g = (b & 7) * ((HEADS * NNODES / 4) / 8) + (b >> 3);
    int h = g / (NNODES / 4);
    int n = (g % (NNODES / 4)) * 4 + (threadIdx.x >> 6);
    int lane = threadIdx.x & 63;
    const float* hrow = Hb + ((size_t)h * NNODES + n) * STRIDE;
    float s = 0.f, d = 0.f;
    if constexpr (FOUT == 256) {
        f32x4 v = *(const f32x4*)&hrow[lane * 4];
        f32x4 as = *(const f32x4*)&Asrc[h * FOUT + lane * 4];
        f32x4 ad = *(const f32x4*)&Adst[h * FOUT + lane * 4];
        s = v[0] * as[0] + v[1] * as[1] + v[2] * as[2] + v[3] * as[3];
        d = v[0] * ad[0] + v[1] * ad[1] + v[2] * ad[2] + v[3] * ad[3];
    } else {
        for (int o = lane; o < FOUT; o += 64) {
            float v = hrow[o];
            s += v * Asrc[h * FOUT + o];
            d += v * Adst[h * FOUT + o];
        }
    }
#pragma unroll
    for (int sh = 32; sh >= 1; sh >>= 1) {
        s += __shfl_xor(s, sh);
        d += __shfl_xor(d, sh);
    }
    if (lane == 0) { es[h * NNODES + n] = s; ed[h * NNODES + n] = d; }
}

// ---------------------------------------------------------------------------
// Sparse masked-softmax attention aggregate, layers 1/2 (FOUT=256).
// XCD-pinned by head. float4 gathers; fused bf16 hi/lo split output.
// ---------------------------------------------------------------------------
template<int HEADS, bool RES, bool WF32>
__global__ __launch_bounds__(256) void aggregate_kern(const float* __restrict__ Hb,
                                                      const float* __restrict__ es,
                                                      const float* __restrict__ ed,
                                                      const int* __restrict__ deg,
                                                      const int* __restrict__ nbr,
                                                      const float* __restrict__ residual,
                                                      float* __restrict__ outp,
                                                      ushort* __restrict__ outHi,
                                                      ushort* __restrict__ outLo) {
    constexpr int FOUT = 256;
    int b = blockIdx.x;
    int g = (b & 7) * ((HEADS * NNODES / 4) / 8) + (b >> 3);
    int h = g / (NNODES / 4);
    int n = (g % (NNODES / 4)) * 4 + (threadIdx.x >> 6);
    int lane = threadIdx.x & 63;
    int d = deg[n];
    const int* nb = nbr + (size_t)n * MAXD;
    float esn = es[h * NNODES + n];
    float sc[2];
    int nm[2];
    float mx = -INFINITY;
#pragma unroll
    for (int r = 0; r < 2; r++) {
        int j = lane + r * 64;
        int m = (j < d) ? nb[j] : 0;
        nm[r] = m;
        float e = -INFINITY;
        if (j < d) {
            float t = esn + ed[h * NNODES + m];
            e = (t > 0.f) ? t : 0.2f * t;
        }
        sc[r] = e;
        mx = fmaxf(mx, e);
    }
#pragma unroll
    for (int sh = 32; sh >= 1; sh >>= 1) mx = fmaxf(mx, __shfl_xor(mx, sh));
    float sum = 0.f;
#pragma unroll
    for (int r = 0; r < 2; r++) {
        float ex = (sc[r] == -INFINITY) ? 0.f : expf(sc[r] - mx);
        sc[r] = ex;
        sum += ex;
    }
#pragma unroll
    for (int sh = 32; sh >= 1; sh >>= 1) sum += __shfl_xor(sum, sh);
    float inv = 1.f / sum;
    sc[0] *= inv; sc[1] *= inv;
    f32x4 acc = {};
    for (int j = 0; j < d; j++) {
        float a = __shfl(sc[j >> 6], j & 63);
        int m = __shfl(nm[j >> 6], j & 63);
        f32x4 v = *(const f32x4*)&Hb[((size_t)h * NNODES + m) * FOUT + lane * 4];
        acc += a * v;
    }
    size_t idx = (size_t)n * (HEADS * FOUT) + (size_t)h * FOUT + lane * 4;
    f32x4 o4;
    u16x4 hi4, lo4;
    if (RES) {
        f32x4 res = *(const f32x4*)&residual[idx];
#pragma unroll
        for (int i = 0; i < 4; i++) {
            float v = acc[i];
            v = (v > 0.f) ? v : (expf(v) - 1.f);
            v += res[i];
            o4[i] = v;
            ushort hi = f32_to_bf16_rne(v);
            hi4[i] = hi;
            lo4[i] = f32_to_bf16_rne(v - bf16_to_f32(hi));
        }
    } else {
#pragma unroll
        for (int i = 0; i < 4; i++) {
            float v = acc[i];
            v = (v > 0.f) ? v : (expf(v) - 1.f);
            o4[i] = v;
            ushort hi = f32_to_bf16_rne(v);
            hi4[i] = hi;
            lo4[i] = f32_to_bf16_rne(v - bf16_to_f32(hi));
        }
    }
    if (WF32) *(f32x4*)&outp[idx] = o4;
    *(u16x4*)&outHi[idx] = hi4;
    *(u16x4*)&outLo[idx] = lo4;
}

// ---------------------------------------------------------------------------
// Layer 3a: per-(h,n) pinned aggregate -> agg[h][n][128] (fp32, stride 128).
// Hb stride 128, cols 121..127 are exact zeros. float2 gathers.
// ---------------------------------------------------------------------------
__global__ __launch_bounds__(256) void aggregate3a_kern(const float* __restrict__ Hb,
                                                        const float* __restrict__ es,
                                                        const float* __restrict__ ed,
                                                        const int* __restrict__ deg,
                                                        const int* __restrict__ nbr,
                                                        float* __restrict__ agg) {
    constexpr int HEADS = 6;
    int b = blockIdx.x;
    int g = (b & 7) * ((HEADS * NNODES / 4) / 8) + (b >> 3);
    int h = g / (NNODES / 4);
    int n = (g % (NNODES / 4)) * 4 + (threadIdx.x >> 6);
    int lane = threadIdx.x & 63;
    int d = deg[n];
    const int* nb = nbr + (size_t)n * MAXD;
    float esn = es[h * NNODES + n];
    float sc[2];
    int nm[2];
    float mx = -INFINITY;
#pragma unroll
    for (int r = 0; r < 2; r++) {
        int j = lane + r * 64;
        int m = (j < d) ? nb[j] : 0;
        nm[r] = m;
        float e = -INFINITY;
        if (j < d) {
            float t = esn + ed[h * NNODES + m];
            e = (t > 0.f) ? t : 0.2f * t;
        }
        sc[r] = e;
        mx = fmaxf(mx, e);
    }
#pragma unroll
    for (int sh = 32; sh >= 1; sh >>= 1) mx = fmaxf(mx, __shfl_xor(mx, sh));
    float sum = 0.f;
#pragma unroll
    for (int r = 0; r < 2; r++) {
        float ex = (sc[r] == -INFINITY) ? 0.f : expf(sc[r] - mx);
        sc[r] = ex;
        sum += ex;
    }
#pragma unroll
    for (int sh = 32; sh >= 1; sh >>= 1) sum += __shfl_xor(sum, sh);
    float inv = 1.f / sum;
    sc[0] *= inv; sc[1] *= inv;
    f32x2 acc = {};
    int c0 = lane * 2;
    for (int j = 0; j < d; j++) {
        float a = __shfl(sc[j >> 6], j & 63);
        int m = __shfl(nm[j >> 6], j & 63);
        f32x2 v = *(const f32x2*)&Hb[((size_t)h * NNODES + m) * 128 + c0];
        acc += a * v;
    }
    *(f32x2*)&agg[((size_t)h * NNODES + n) * 128 + c0] = acc;
}

// ---------------------------------------------------------------------------
// Layer 3b: mean over 6 heads + row log_softmax (121 classes). 1 wave/node.
// ---------------------------------------------------------------------------
__global__ __launch_bounds__(256) void reduce3_kern(const float* __restrict__ agg,
                                                    float* __restrict__ outp) {
    constexpr int FOUT = 121;
    int n = blockIdx.x * 4 + (threadIdx.x >> 6);
    int lane = threadIdx.x & 63;
    int c0 = lane * 2;
    f32x2 l = {};
#pragma unroll
    for (int h = 0; h < 6; h++)
        l += *(const f32x2*)&agg[((size_t)h * NNODES + n) * 128 + c0];
    l = l * (1.f / 6.f);
    float m0 = (c0 < FOUT) ? l[0] : -INFINITY;
    float m1 = (c0 + 1 < FOUT) ? l[1] : -INFINITY;
    float mx = fmaxf(m0, m1);
#pragma unroll
    for (int sh = 32; sh >= 1; sh >>= 1) mx = fmaxf(mx, __shfl_xor(mx, sh));
    float s = ((c0 < FOUT) ? expf(l[0] - mx) : 0.f) + ((c0 + 1 < FOUT) ? expf(l[1] - mx) : 0.f);
#pragma unroll
    for (int sh = 32; sh >= 1; sh >>= 1) s += __shfl_xor(s, sh);
    float lse = logf(s);
    if (c0 < FOUT) outp[(size_t)n * FOUT + c0] = l[0] - mx - lse;
    if (c0 + 1 < FOUT) outp[(size_t)n * FOUT + c0 + 1] = l[1] - mx - lse;
}

// ---------------------------------------------------------------------------
extern "C" void kernel_launch(void* const* d_in, const int* in_sizes, int n_in,
                              void* d_out, int out_size, void* d_ws, size_t ws_size,
                              hipStream_t stream) {
    const float* x   = (const float*)d_in[0];
    const int*   adj = (const int*)d_in[1];
    const float* W1  = (const float*)d_in[2];
    const float* a1s = (const float*)d_in[3];
    const float* a1d = (const float*)d_in[4];
    const float* W2  = (const float*)d_in[5];
    const float* a2s = (const float*)d_in[6];
    const float* a2d = (const float*)d_in[7];
    const float* W3  = (const float*)d_in[8];
    const float* a3s = (const float*)d_in[9];
    const float* a3d = (const float*)d_in[10];
    float* outp = (float*)d_out;

    char* w = (char*)d_ws;
    int* deg = (int*)w;      w += (size_t)NNODES * sizeof(int);
    int* nbr = (int*)w;      w += (size_t)NNODES * MAXD * sizeof(int);
    float* hbuf = (float*)w; w += (size_t)4 * NNODES * 256 * sizeof(float);  // 16 MB (fits 6*N*128 too)
    float* es = (float*)w;   w += (size_t)6 * NNODES * sizeof(float);
    float* ed = (float*)w;   w += (size_t)6 * NNODES * sizeof(float);
    float* x1 = (float*)w;   w += (size_t)NNODES * 1024 * sizeof(float);
    ushort* Xhi = (ushort*)w; w += (size_t)NNODES * 1024 * sizeof(ushort);   // shared for x/x1/x2
    ushort* Xlo = (ushort*)w; w += (size_t)NNODES * 1024 * sizeof(ushort);
    ushort* W1h = (ushort*)w; w += (size_t)4 * 256 * 64 * sizeof(ushort);
    ushort* W1l = (ushort*)w; w += (size_t)4 * 256 * 64 * sizeof(ushort);
    ushort* W2h = (ushort*)w; w += (size_t)4 * 256 * 1024 * sizeof(ushort);
    ushort* W2l = (ushort*)w; w += (size_t)4 * 256 * 1024 * sizeof(ushort);
    ushort* W3h = (ushort*)w; w += (size_t)6 * 128 * 1024 * sizeof(ushort);
    ushort* W3l = (ushort*)w; w += (size_t)6 * 128 * 1024 * sizeof(ushort);
    // agg[6][4096][128] fp32 (12.6 MB) aliases Xhi/Xlo (16 MB): dead after L3 GEMM.
    float* agg = (float*)Xhi;

    build_csr<<<NNODES, 256, 0, stream>>>(adj, deg, nbr);

    // Weight transpose+split (independent of layer outputs)
    wsplit<<<dim3(2, 8, 4), 256, 0, stream>>>(W1, W1h, W1l, 50, 64, 256, 256);
    wsplit<<<dim3(32, 8, 4), 256, 0, stream>>>(W2, W2h, W2l, 1024, 1024, 256, 256);
    wsplit<<<dim3(32, 4, 6), 256, 0, stream>>>(W3, W3h, W3l, 1024, 1024, 121, 128);

    // ---- Layer 1: x[4096,50] -> x1[4096,1024]
    xsplit<<<1024, 256, 0, stream>>>(x, Xhi, Xlo, NNODES, 50, 6);
    gemm_mfma<<<32 * 4 * 4, 256, 0, stream>>>(Xhi, Xlo, W1h, W1l, hbuf, 64, 256, 256, 4);
    scores_kern<256, 256, 4><<<4 * NNODES / 4, 256, 0, stream>>>(hbuf, a1s, a1d, es, ed);
    aggregate_kern<4, false, true><<<4 * NNODES / 4, 256, 0, stream>>>(
        hbuf, es, ed, deg, nbr, nullptr, x1, Xhi, Xlo);

    // ---- Layer 2: x1 -> x2 = ELU(gat(x1)) + x1   (split written directly)
    gemm_mfma<<<32 * 4 * 4, 256, 0, stream>>>(Xhi, Xlo, W2h, W2l, hbuf, 1024, 256, 256, 4);
    scores_kern<256, 256, 4><<<4 * NNODES / 4, 256, 0, stream>>>(hbuf, a2s, a2d, es, ed);
    aggregate_kern<4, true, false><<<4 * NNODES / 4, 256, 0, stream>>>(
        hbuf, es, ed, deg, nbr, x1, nullptr, Xhi, Xlo);

    // ---- Layer 3: x2 -> out = log_softmax(mean_h gat(x2)); Hb stride 128
    gemm_mfma<<<32 * 2 * 6, 256, 0, stream>>>(Xhi, Xlo, W3h, W3l, hbuf, 1024, 128, 128, 2);
    scores_kern<121, 128, 6><<<6 * NNODES / 4, 256, 0, stream>>>(hbuf, a3s, a3d, es, ed);
    aggregate3a_kern<<<6 * NNODES / 4, 256, 0, stream>>>(hbuf, es, ed, deg, nbr, agg);
    reduce3_kern<<<NNODES / 4, 256, 0, stream>>>(agg, outp);
}

// Round 6
// 207.059 us; speedup vs baseline: 2.8500x; 1.0260x over previous
//
#include <hip/hip_runtime.h>
#include <hip/hip_bf16.h>
#include <math.h>

#define NNODES 4096
#define MAXD 128

typedef __attribute__((ext_vector_type(8))) short bf16x8;
typedef __attribute__((ext_vector_type(4))) float f32x4;
typedef __attribute__((ext_vector_type(2))) float f32x2;
typedef __attribute__((ext_vector_type(16))) float f32x16;
typedef __attribute__((ext_vector_type(4))) ushort u16x4;

__device__ inline ushort f32_to_bf16_rne(float f) {
    uint32_t u = __float_as_uint(f);
    u += 0x7FFFu + ((u >> 16) & 1u);
    return (ushort)(u >> 16);
}
__device__ inline float bf16_to_f32(ushort h) {
    return __uint_as_float((uint32_t)h << 16);
}

// ---------------------------------------------------------------------------
// CSR build: one block per row, deterministic ordered compaction. int4 loads.
// ---------------------------------------------------------------------------
__global__ __launch_bounds__(256) void build_csr(const int* __restrict__ adj,
                                                 int* __restrict__ deg,
                                                 int* __restrict__ nbr) {
    int n = blockIdx.x;
    const int* row = adj + (size_t)n * NNODES;
    int t = threadIdx.x;
    __shared__ int cnts[256];
    int c0 = t * 16;
    int vals[16];
    const int4* r4 = (const int4*)(row + c0);
#pragma unroll
    for (int i = 0; i < 4; i++) {
        int4 v = r4[i];
        vals[4 * i] = v.x; vals[4 * i + 1] = v.y; vals[4 * i + 2] = v.z; vals[4 * i + 3] = v.w;
    }
    int cnt = 0;
#pragma unroll
    for (int i = 0; i < 16; i++) cnt += (vals[i] != 0) ? 1 : 0;
    cnts[t] = cnt;
    __syncthreads();
    if (t == 0) {
        int s = 0;
        for (int i = 0; i < 256; i++) { int c = cnts[i]; cnts[i] = s; s += c; }
        deg[n] = (s < MAXD) ? s : MAXD;
    }
    __syncthreads();
    int o = cnts[t];
    int* outr = nbr + (size_t)n * MAXD;
#pragma unroll
    for (int i = 0; i < 16; i++) {
        if (vals[i] != 0) {
            if (o < MAXD) outr[o] = c0 + i;
            o++;
        }
    }
}

// ---------------------------------------------------------------------------
// Split X [M][K] fp32 -> hi/lo bf16 [M][KP] (zero-pad k>=K). KP power of 2.
// ---------------------------------------------------------------------------
__global__ __launch_bounds__(256) void xsplit(const float* __restrict__ X,
                                              ushort* __restrict__ Xhi,
                                              ushort* __restrict__ Xlo,
                                              int M, int K, int KP_log2) {
    int KP = 1 << KP_log2;
    int total = M << KP_log2;
    for (int i = blockIdx.x * 256 + threadIdx.x; i < total; i += gridDim.x * 256) {
        int k = i & (KP - 1);
        int m = i >> KP_log2;
        float v = (k < K) ? X[(size_t)m * K + k] : 0.f;
        ushort hi = f32_to_bf16_rne(v);
        float hf = bf16_to_f32(hi);
        Xhi[i] = hi;
        Xlo[i] = f32_to_bf16_rne(v - hf);
    }
}

// ---------------------------------------------------------------------------
// Transpose-split W [H][K][N] fp32 -> Wt hi/lo [H][NP][KP] bf16, zero-padded.
// ---------------------------------------------------------------------------
__global__ __launch_bounds__(256) void wsplit(const float* __restrict__ W,
                                              ushort* __restrict__ Whi,
                                              ushort* __restrict__ Wlo,
                                              int K, int KP, int N, int NP) {
    __shared__ float tile[32][33];
    int h = blockIdx.z;
    int k0 = blockIdx.x * 32, n0 = blockIdx.y * 32;
    int tid = threadIdx.x;
    const float* Wh_ = W + (size_t)h * K * N;
#pragma unroll
    for (int r = 0; r < 4; r++) {
        int kl = (tid >> 5) + r * 8;
        int nl = tid & 31;
        int k = k0 + kl, n = n0 + nl;
        tile[kl][nl] = (k < K && n < N) ? Wh_[(size_t)k * N + n] : 0.f;
    }
    __syncthreads();
#pragma unroll
    for (int r = 0; r < 4; r++) {
        int nl = (tid >> 5) + r * 8;
        int kl = tid & 31;
        float v = tile[kl][nl];
        ushort hi = f32_to_bf16_rne(v);
        float hf = bf16_to_f32(hi);
        ushort lo = f32_to_bf16_rne(v - hf);
        size_t o = ((size_t)h * NP + n0 + nl) * KP + k0 + kl;
        Whi[o] = hi;
        Wlo[o] = lo;
    }
}

// ---------------------------------------------------------------------------
// Split-precision bf16 MFMA GEMM, XCD-pinned by head via 1D grid remap.
// Block 128x128, 4 waves (2x2), wave tile 64x64 of 2x2 32x32x16 frags.
// BK=64, double-buffered LDS (one barrier/step), register prefetch.
// h = Xhi*Whi + Xhi*Wlo + Xlo*Whi  (fp32 accumulate) ~ fp32 accuracy.
// ---------------------------------------------------------------------------
__global__ __launch_bounds__(256, 1) void gemm_mfma(const ushort* __restrict__ Xhi,
                                                    const ushort* __restrict__ Xlo,
                                                    const ushort* __restrict__ Whi,
                                                    const ushort* __restrict__ Wlo,
                                                    float* __restrict__ Hb,
                                                    int KP, int NP, int Nstride, int nby) {
    extern __shared__ ushort lds[];
    // ushort offsets within one buffer: Ah 0, Al 9216, Bh 18432, Bl 27648
    constexpr int AH = 0, AL = 9216, BH = 18432, BL = 27648, BUF = 36864;
    int b = blockIdx.x;
    int perx = gridDim.x >> 3;
    int g = (b & 7) * perx + (b >> 3);
    int per_head = 32 * nby;
    int h = g / per_head;
    int r0 = g - h * per_head;
    const int m0 = (r0 / nby) * 128;
    const int n0 = (r0 % nby) * 128;
    const int tid = threadIdx.x;
    const int lane = tid & 63;
    const int w = tid >> 6;
    const int wr = (w >> 1) * 64, wc = (w & 1) * 64;
    const int fr = lane & 31;     // row (A) / col (B) within 32-frag
    const int fg = lane >> 5;     // k-half selector
    const ushort* Wh_ = Whi + (size_t)h * NP * KP;
    const ushort* Wl_ = Wlo + (size_t)h * NP * KP;
    const int sr = tid >> 3;            // 0..31
    const int sc8 = (tid & 7) * 8;      // 0..56
    bf16x8 pa_h[4], pa_l[4], pb_h[4], pb_l[4];
    auto LOADG = [&](int K0) {
#pragma unroll
        for (int i = 0; i < 4; i++) {
            size_t ra = (size_t)(m0 + sr + 32 * i) * KP + K0 + sc8;
            pa_h[i] = *(const bf16x8*)&Xhi[ra];
            pa_l[i] = *(const bf16x8*)&Xlo[ra];
            size_t rb = (size_t)(n0 + sr + 32 * i) * KP + K0 + sc8;
            pb_h[i] = *(const bf16x8*)&Wh_[rb];
            pb_l[i] = *(const bf16x8*)&Wl_[rb];
        }
    };
    LOADG(0);
    f32x16 acc[2][2] = {};
    int cur = 0;
    for (int k0 = 0; k0 < KP; k0 += 64) {
        const int bo = cur * BUF;
#pragma unroll
        for (int i = 0; i < 4; i++) {
            int r = (sr + 32 * i) * 72 + sc8;
            *(bf16x8*)&lds[bo + AH + r] = pa_h[i];
            *(bf16x8*)&lds[bo + AL + r] = pa_l[i];
            *(bf16x8*)&lds[bo + BH + r] = pb_h[i];
            *(bf16x8*)&lds[bo + BL + r] = pb_l[i];
        }
        if (k0 + 64 < KP) LOADG(k0 + 64);
        __syncthreads();
#pragma unroll
        for (int ks = 0; ks < 4; ks++) {
            const int kc = ks * 16 + fg * 8;
            bf16x8 ah[2], al[2], bh[2], bl[2];
#pragma unroll
            for (int i = 0; i < 2; i++) {
                ah[i] = *(const bf16x8*)&lds[bo + AH + (wr + i * 32 + fr) * 72 + kc];
                al[i] = *(const bf16x8*)&lds[bo + AL + (wr + i * 32 + fr) * 72 + kc];
                bh[i] = *(const bf16x8*)&lds[bo + BH + (wc + i * 32 + fr) * 72 + kc];
                bl[i] = *(const bf16x8*)&lds[bo + BL + (wc + i * 32 + fr) * 72 + kc];
            }
#pragma unroll
            for (int i = 0; i < 2; i++)
#pragma unroll
                for (int j = 0; j < 2; j++) {
                    acc[i][j] = __builtin_amdgcn_mfma_f32_32x32x16_bf16(ah[i], bh[j], acc[i][j], 0, 0, 0);
                    acc[i][j] = __builtin_amdgcn_mfma_f32_32x32x16_bf16(ah[i], bl[j], acc[i][j], 0, 0, 0);
                    acc[i][j] = __builtin_amdgcn_mfma_f32_32x32x16_bf16(al[i], bh[j], acc[i][j], 0, 0, 0);
                }
        }
        cur ^= 1;
    }
    // epilogue: 32x32 C/D layout: col=lane&31, row=(reg&3)+8*(reg>>2)+4*(lane>>5)
#pragma unroll
    for (int i = 0; i < 2; i++)
#pragma unroll
        for (int j = 0; j < 2; j++)
#pragma unroll
            for (int reg = 0; reg < 16; reg++) {
                int row = m0 + wr + i * 32 + (reg & 3) + 8 * (reg >> 2) + 4 * fg;
                int col = n0 + wc + j * 32 + fr;
                Hb[((size_t)h * NNODES + row) * Nstride + col] = acc[i][j][reg];
            }
}

// ---------------------------------------------------------------------------
// es[h][n] = dot(H[h][n][:], a_src[h]); ed likewise. One wave per (h,n).
// ---------------------------------------------------------------------------
template<int FOUT, int STRIDE, int HEADS>
__global__ __launch_bounds__(256) void scores_kern(const float* __restrict__ Hb,
                                                   const float* __restrict__ Asrc,
                                                   const float* __restrict__ Adst,
                                                   float* __restrict__ es,
                                                   float* __restrict__ ed) {
    int b = blockIdx.x;
    int g = (b & 7) * ((HEADS * NNODES / 4) / 8) + (b >> 3);
    int h = g / (NNODES / 4);
    int n = (g % (NNODES / 4)) * 4 + (threadIdx.x >> 6);
    int lane = threadIdx.x & 63;
    const float* hrow = Hb + ((size_t)h * NNODES + n) * STRIDE;
    float s = 0.f, d = 0.f;
    if constexpr (FOUT == 256) {
        f32x4 v = *(const f32x4*)&hrow[lane * 4];
        f32x4 as = *(const f32x4*)&Asrc[h * FOUT + lane * 4];
        f32x4 ad = *(const f32x4*)&Adst[h * FOUT + lane * 4];
        s = v[0] * as[0] + v[1] * as[1] + v[2] * as[2] + v[3] * as[3];
        d = v[0] * ad[0] + v[1] * ad[1] + v[2] * ad[2] + v[3] * ad[3];
    } else {
        for (int o = lane; o < FOUT; o += 64) {
            float v = hrow[o];
            s += v * Asrc[h * FOUT + o];
            d += v * Adst[h * FOUT + o];
        }
    }
#pragma unroll
    for (int sh = 32; sh >= 1; sh >>= 1) {
        s += __shfl_xor(s, sh);
        d += __shfl_xor(d, sh);
    }
    if (lane == 0) { es[h * NNODES + n] = s; ed[h * NNODES + n] = d; }
}

// ---------------------------------------------------------------------------
// Sparse masked-softmax attention aggregate, layers 1/2 (FOUT=256).
// XCD-pinned by head. float4 gathers; fused bf16 hi/lo split output.
// ---------------------------------------------------------------------------
template<int HEADS, bool RES, bool WF32>
__global__ __launch_bounds__(256) void aggregate_kern(const float* __restrict__ Hb,
                                                      const float* __restrict__ es,
                                                      const float* __restrict__ ed,
                                                      const int* __restrict__ deg,
                                                      const int* __restrict__ nbr,
                                                      const float* __restrict__ residual,
                                                      float* __restrict__ outp,
                                                      ushort* __restrict__ outHi,
                                                      ushort* __restrict__ outLo) {
    constexpr int FOUT = 256;
    int b = blockIdx.x;
    int g = (b & 7) * ((HEADS * NNODES / 4) / 8) + (b >> 3);
    int h = g / (NNODES / 4);
    int n = (g % (NNODES / 4)) * 4 + (threadIdx.x >> 6);
    int lane = threadIdx.x & 63;
    int d = deg[n];
    const int* nb = nbr + (size_t)n * MAXD;
    float esn = es[h * NNODES + n];
    float sc[2];
    int nm[2];
    float mx = -INFINITY;
#pragma unroll
    for (int r = 0; r < 2; r++) {
        int j = lane + r * 64;
        int m = (j < d) ? nb[j] : 0;
        nm[r] = m;
        float e = -INFINITY;
        if (j < d) {
            float t = esn + ed[h * NNODES + m];
            e = (t > 0.f) ? t : 0.2f * t;
        }
        sc[r] = e;
        mx = fmaxf(mx, e);
    }
#pragma unroll
    for (int sh = 32; sh >= 1; sh >>= 1) mx = fmaxf(mx, __shfl_xor(mx, sh));
    float sum = 0.f;
#pragma unroll
    for (int r = 0; r < 2; r++) {
        float ex = (sc[r] == -INFINITY) ? 0.f : expf(sc[r] - mx);
        sc[r] = ex;
        sum += ex;
    }
#pragma unroll
    for (int sh = 32; sh >= 1; sh >>= 1) sum += __shfl_xor(sum, sh);
    float inv = 1.f / sum;
    sc[0] *= inv; sc[1] *= inv;
    f32x4 acc = {};
    for (int j = 0; j < d; j++) {
        float a = __shfl(sc[j >> 6], j & 63);
        int m = __shfl(nm[j >> 6], j & 63);
        f32x4 v = *(const f32x4*)&Hb[((size_t)h * NNODES + m) * FOUT + lane * 4];
        acc += a * v;
    }
    size_t idx = (size_t)n * (HEADS * FOUT) + (size_t)h * FOUT + lane * 4;
    f32x4 o4;
    u16x4 hi4, lo4;
    if (RES) {
        f32x4 res = *(const f32x4*)&residual[idx];
#pragma unroll
        for (int i = 0; i < 4; i++) {
            float v = acc[i];
            v = (v > 0.f) ? v : (expf(v) - 1.f);
            v += res[i];
            o4[i] = v;
            ushort hi = f32_to_bf16_rne(v);
            hi4[i] = hi;
            lo4[i] = f32_to_bf16_rne(v - bf16_to_f32(hi));
        }
    } else {
#pragma unroll
        for (int i = 0; i < 4; i++) {
            float v = acc[i];
            v = (v > 0.f) ? v : (expf(v) - 1.f);
            o4[i] = v;
            ushort hi = f32_to_bf16_rne(v);
            hi4[i] = hi;
            lo4[i] = f32_to_bf16_rne(v - bf16_to_f32(hi));
        }
    }
    if (WF32) *(f32x4*)&outp[idx] = o4;
    *(u16x4*)&outHi[idx] = hi4;
    *(u16x4*)&outLo[idx] = lo4;
}

// ---------------------------------------------------------------------------
// Layer 3a: per-(h,n) pinned aggregate -> agg[h][n][128] (fp32, stride 128).
// Hb stride 128, cols 121..127 are exact zeros. float2 gathers.
// ---------------------------------------------------------------------------
__global__ __launch_bounds__(256) void aggregate3a_kern(const float* __restrict__ Hb,
                                                        const float* __restrict__ es,
                                                        const float* __restrict__ ed,
                                                        const int* __restrict__ deg,
                                                        const int* __restrict__ nbr,
                                                        float* __restrict__ agg) {
    constexpr int HEADS = 6;
    int b = blockIdx.x;
    int g = (b & 7) * ((HEADS * NNODES / 4) / 8) + (b >> 3);
    int h = g / (NNODES / 4);
    int n = (g % (NNODES / 4)) * 4 + (threadIdx.x >> 6);
    int lane = threadIdx.x & 63;
    int d = deg[n];
    const int* nb = nbr + (size_t)n * MAXD;
    float esn = es[h * NNODES + n];
    float sc[2];
    int nm[2];
    float mx = -INFINITY;
#pragma unroll
    for (int r = 0; r < 2; r++) {
        int j = lane + r * 64;
        int m = (j < d) ? nb[j] : 0;
        nm[r] = m;
        float e = -INFINITY;
        if (j < d) {
            float t = esn + ed[h * NNODES + m];
            e = (t > 0.f) ? t : 0.2f * t;
        }
        sc[r] = e;
        mx = fmaxf(mx, e);
    }
#pragma unroll
    for (int sh = 32; sh >= 1; sh >>= 1) mx = fmaxf(mx, __shfl_xor(mx, sh));
    float sum = 0.f;
#pragma unroll
    for (int r = 0; r < 2; r++) {
        float ex = (sc[r] == -INFINITY) ? 0.f : expf(sc[r] - mx);
        sc[r] = ex;
        sum += ex;
    }
#pragma unroll
    for (int sh = 32; sh >= 1; sh >>= 1) sum += __shfl_xor(sum, sh);
    float inv = 1.f / sum;
    sc[0] *= inv; sc[1] *= inv;
    f32x2 acc = {};
    int c0 = lane * 2;
    for (int j = 0; j < d; j++) {
        float a = __shfl(sc[j >> 6], j & 63);
        int m = __shfl(nm[j >> 6], j & 63);
        f32x2 v = *(const f32x2*)&Hb[((size_t)h * NNODES + m) * 128 + c0];
        acc += a * v;
    }
    *(f32x2*)&agg[((size_t)h * NNODES + n) * 128 + c0] = acc;
}

// ---------------------------------------------------------------------------
// Layer 3b: mean over 6 heads + row log_softmax (121 classes). 1 wave/node.
// ---------------------------------------------------------------------------
__global__ __launch_bounds__(256) void reduce3_kern(const float* __restrict__ agg,
                                                    float* __restrict__ outp) {
    constexpr int FOUT = 121;
    int n = blockIdx.x * 4 + (threadIdx.x >> 6);
    int lane = threadIdx.x & 63;
    int c0 = lane * 2;
    f32x2 l = {};
#pragma unroll
    for (int h = 0; h < 6; h++)
        l += *(const f32x2*)&agg[((size_t)h * NNODES + n) * 128 + c0];
    l = l * (1.f / 6.f);
    float m0 = (c0 < FOUT) ? l[0] : -INFINITY;
    float m1 = (c0 + 1 < FOUT) ? l[1] : -INFINITY;
    float mx = fmaxf(m0, m1);
#pragma unroll
    for (int sh = 32; sh >= 1; sh >>= 1) mx = fmaxf(mx, __shfl_xor(mx, sh));
    float s = ((c0 < FOUT) ? expf(l[0] - mx) : 0.f) + ((c0 + 1 < FOUT) ? expf(l[1] - mx) : 0.f);
#pragma unroll
    for (int sh = 32; sh >= 1; sh >>= 1) s += __shfl_xor(s, sh);
    float lse = logf(s);
    if (c0 < FOUT) outp[(size_t)n * FOUT + c0] = l[0] - mx - lse;
    if (c0 + 1 < FOUT) outp[(size_t)n * FOUT + c0 + 1] = l[1] - mx - lse;
}

// ---------------------------------------------------------------------------
extern "C" void kernel_launch(void* const* d_in, const int* in_sizes, int n_in,
                              void* d_out, int out_size, void* d_ws, size_t ws_size,
                              hipStream_t stream) {
    const float* x   = (const float*)d_in[0];
    const int*   adj = (const int*)d_in[1];
    const float* W1  = (const float*)d_in[2];
    const float* a1s = (const float*)d_in[3];
    const float* a1d = (const float*)d_in[4];
    const float* W2  = (const float*)d_in[5];
    const float* a2s = (const float*)d_in[6];
    const float* a2d = (const float*)d_in[7];
    const float* W3  = (const float*)d_in[8];
    const float* a3s = (const float*)d_in[9];
    const float* a3d = (const float*)d_in[10];
    float* outp = (float*)d_out;

    char* w = (char*)d_ws;
    int* deg = (int*)w;      w += (size_t)NNODES * sizeof(int);
    int* nbr = (int*)w;      w += (size_t)NNODES * MAXD * sizeof(int);
    float* hbuf = (float*)w; w += (size_t)4 * NNODES * 256 * sizeof(float);  // 16 MB (fits 6*N*128 too)
    float* es = (float*)w;   w += (size_t)6 * NNODES * sizeof(float);
    float* ed = (float*)w;   w += (size_t)6 * NNODES * sizeof(float);
    float* x1 = (float*)w;   w += (size_t)NNODES * 1024 * sizeof(float);
    ushort* Xhi = (ushort*)w; w += (size_t)NNODES * 1024 * sizeof(ushort);   // shared for x/x1/x2
    ushort* Xlo = (ushort*)w; w += (size_t)NNODES * 1024 * sizeof(ushort);
    ushort* W1h = (ushort*)w; w += (size_t)4 * 256 * 64 * sizeof(ushort);
    ushort* W1l = (ushort*)w; w += (size_t)4 * 256 * 64 * sizeof(ushort);
    ushort* W2h = (ushort*)w; w += (size_t)4 * 256 * 1024 * sizeof(ushort);
    ushort* W2l = (ushort*)w; w += (size_t)4 * 256 * 1024 * sizeof(ushort);
    ushort* W3h = (ushort*)w; w += (size_t)6 * 128 * 1024 * sizeof(ushort);
    ushort* W3l = (ushort*)w; w += (size_t)6 * 128 * 1024 * sizeof(ushort);
    // agg[6][4096][128] fp32 (12.6 MB) aliases Xhi/Xlo (16 MB): dead after L3 GEMM.
    float* agg = (float*)Xhi;

    constexpr size_t GEMM_LDS = 2u * 4u * 128u * 72u * sizeof(ushort);  // 147456 B

    build_csr<<<NNODES, 256, 0, stream>>>(adj, deg, nbr);

    // Weight transpose+split (independent of layer outputs)
    wsplit<<<dim3(2, 8, 4), 256, 0, stream>>>(W1, W1h, W1l, 50, 64, 256, 256);
    wsplit<<<dim3(32, 8, 4), 256, 0, stream>>>(W2, W2h, W2l, 1024, 1024, 256, 256);
    wsplit<<<dim3(32, 4, 6), 256, 0, stream>>>(W3, W3h, W3l, 1024, 1024, 121, 128);

    // ---- Layer 1: x[4096,50] -> x1[4096,1024]
    xsplit<<<1024, 256, 0, stream>>>(x, Xhi, Xlo, NNODES, 50, 6);
    gemm_mfma<<<256, 256, GEMM_LDS, stream>>>(Xhi, Xlo, W1h, W1l, hbuf, 64, 256, 256, 2);
    scores_kern<256, 256, 4><<<4 * NNODES / 4, 256, 0, stream>>>(hbuf, a1s, a1d, es, ed);
    aggregate_kern<4, false, true><<<4 * NNODES / 4, 256, 0, stream>>>(
        hbuf, es, ed, deg, nbr, nullptr, x1, Xhi, Xlo);

    // ---- Layer 2: x1 -> x2 = ELU(gat(x1)) + x1   (split written directly)
    gemm_mfma<<<256, 256, GEMM_LDS, stream>>>(Xhi, Xlo, W2h, W2l, hbuf, 1024, 256, 256, 2);
    scores_kern<256, 256, 4><<<4 * NNODES / 4, 256, 0, stream>>>(hbuf, a2s, a2d, es, ed);
    aggregate_kern<4, true, false><<<4 * NNODES / 4, 256, 0, stream>>>(
        hbuf, es, ed, deg, nbr, x1, nullptr, Xhi, Xlo);

    // ---- Layer 3: x2 -> out = log_softmax(mean_h gat(x2)); Hb stride 128
    gemm_mfma<<<192, 256, GEMM_LDS, stream>>>(Xhi, Xlo, W3h, W3l, hbuf, 1024, 128, 128, 1);
    scores_kern<121, 128, 6><<<6 * NNODES / 4, 256, 0, stream>>>(hbuf, a3s, a3d, es, ed);
    aggregate3a_kern<<<6 * NNODES / 4, 256, 0, stream>>>(hbuf, es, ed, deg, nbr, agg);
    reduce3_kern<<<NNODES / 4, 256, 0, stream>>>(agg, outp);
}